// Round 8
// baseline (3396.785 us; speedup 1.0000x reference)
//
#include <hip/hip_runtime.h>
#include <hip/hip_bf16.h>
#include <math.h>

#define B_ 32
#define NLOC 81
#define SBO 35
#define SPO 40
#define E_ 224
#define NH_ 8
#define DH 28
#define NLAYERS 10
#define LSTM_H 200
#define NACT 13030
#define NPOW 7
#define MAXL 17
#define TOK (B_*NLOC)          // 2592
#define NCOL (B_*NPOW)         // 224
#define NROW (NCOL*MAXL)       // 3808
#define DIST_SIZE (B_*NPOW*MAXL*NACT)  // 49618240 f32 elements
#define MSGK 2000              // MSGLOG*MSGEMB
#define TRANSW_BLOCKS ((75*800 + 255)/256)   // 235

__device__ __forceinline__ float sigm(float x) { return 1.f / (1.f + __expf(-x)); }

// bf16 pack/unpack helpers (RNE)
__device__ __forceinline__ unsigned f2bf(float f) {
  unsigned b = __float_as_uint(f);
  return (b + 0x7fffu + ((b >> 16) & 1u)) >> 16;
}
__device__ __forceinline__ float blo(unsigned u) { return __uint_as_float(u << 16); }
__device__ __forceinline__ float bhi(unsigned u) { return __uint_as_float(u & 0xffff0000u); }

// ---- device-global compaction state (graph-safe, no hipMalloc) ----
__device__ int g_rowmap[NROW];
__device__ int g_nlive;

// ---------------- prep: encoder + recurrent-weight pack + live-row scan (one dispatch) ----------
__global__ __launch_bounds__(256) void prep_kernel(
    const float* __restrict__ x_bo, const float* __restrict__ x_po,
    const float* __restrict__ enc_W, const float* __restrict__ enc_b,
    const float* __restrict__ pos_bias, float* __restrict__ x,
    const float* __restrict__ Whh0, const float* __restrict__ Wih1,
    const float* __restrict__ Whh1, uint4* __restrict__ WTH0,
    uint4* __restrict__ WTH1, const int* __restrict__ locs_len) {
  int bid = blockIdx.x;
  if (bid < TOK) {
    // ---- encoder: x = concat(x_bo,x_po) @ enc_W^T + enc_b + pos_bias ----
    int t = bid;
    int l = t % NLOC;
    __shared__ float in[SBO + SPO];
    if (threadIdx.x < SBO) in[threadIdx.x] = x_bo[(size_t)t*SBO + threadIdx.x];
    else if (threadIdx.x < SBO + SPO) in[threadIdx.x] = x_po[(size_t)t*SPO + threadIdx.x - SBO];
    __syncthreads();
    int e = threadIdx.x;
    if (e < E_) {
      float s = enc_b[e] + pos_bias[l*E_ + e];
      const float* w = enc_W + e*(SBO+SPO);
      for (int k = 0; k < SBO+SPO; ++k) s += in[k] * w[k];
      x[(size_t)t*E_ + e] = s;
    }
  } else if (bid < TOK + TRANSW_BLOCKS) {
    // ---- recurrent-weight transpose+pack to bf16 ----
    int idx = (bid - TOK)*256 + threadIdx.x;
    if (idx >= 75*800) return;
    int k8 = idx / 800, g = idx % 800;
    const float* src;
    uint4* dst;
    if (k8 < 25) {
      src = Whh0 + (size_t)g*LSTM_H + k8*8;
      dst = WTH0 + (size_t)k8*800 + g;
    } else {
      int kk8 = k8 - 25;
      src = (kk8 < 25) ? (Wih1 + (size_t)g*LSTM_H + kk8*8)
                       : (Whh1 + (size_t)g*LSTM_H + (kk8-25)*8);
      dst = WTH1 + (size_t)kk8*800 + g;
    }
    unsigned p[4];
#pragma unroll
    for (int i = 0; i < 4; ++i)
      p[i] = f2bf(src[2*i]) | (f2bf(src[2*i+1]) << 16);
    *dst = make_uint4(p[0], p[1], p[2], p[3]);
  } else {
    // ---- live-row compaction scan ----
    __shared__ int off[NCOL + 1];
    if (threadIdx.x == 0) {
      int acc = 0;
      for (int n = 0; n < NCOL; ++n) { off[n] = acc; acc += locs_len[n]; }
      off[NCOL] = acc;
      g_nlive = acc;
    }
    __syncthreads();
    for (int n = threadIdx.x; n < NCOL; n += 256) {
      int base = off[n], len = locs_len[n];
      for (int s = 0; s < len; ++s) g_rowmap[base + s] = n*MAXL + s;
    }
  }
}

// ---------------- generic GEMM: C[M,N] = A[M,K](f32) @ W[N,K]^T(f32) + bias ----------------
#define GBM 64
#define GBN 64
#define GBK 16
template<int RELU>
__global__ __launch_bounds__(256) void gemm_kernel(
    const float* __restrict__ A, const float* __restrict__ W,
    const float* __restrict__ bias, float* __restrict__ C,
    int M, int N, int K) {
  __shared__ float As[GBK][GBM+4];
  __shared__ float Ws[GBK][GBN+4];
  int tid = threadIdx.x;
  int tx = tid & 15, ty = tid >> 4;
  int row0 = blockIdx.y * GBM, col0 = blockIdx.x * GBN;
  float acc[4][4] = {};
  for (int k0 = 0; k0 < K; k0 += GBK) {
    for (int i = tid; i < GBM*GBK; i += 256) {
      int m = i >> 4, kk = i & 15;
      int gm = row0 + m, gk = k0 + kk;
      As[kk][m] = (gm < M && gk < K) ? A[(size_t)gm*K + gk] : 0.f;
    }
    for (int i = tid; i < GBN*GBK; i += 256) {
      int n = i >> 4, kk = i & 15;
      int gn = col0 + n, gk = k0 + kk;
      Ws[kk][n] = (gn < N && gk < K) ? W[(size_t)gn*K + gk] : 0.f;
    }
    __syncthreads();
#pragma unroll
    for (int kk = 0; kk < GBK; ++kk) {
      float4 av = *(const float4*)&As[kk][ty*4];
      float4 wv = *(const float4*)&Ws[kk][tx*4];
      float a_[4] = {av.x, av.y, av.z, av.w};
      float w_[4] = {wv.x, wv.y, wv.z, wv.w};
#pragma unroll
      for (int i = 0; i < 4; ++i)
#pragma unroll
        for (int j = 0; j < 4; ++j)
          acc[i][j] += a_[i] * w_[j];
    }
    __syncthreads();
  }
#pragma unroll
  for (int i = 0; i < 4; ++i) {
    int gm = row0 + ty*4 + i;
    if (gm >= M) continue;
#pragma unroll
    for (int j = 0; j < 4; ++j) {
      int gn = col0 + tx*4 + j;
      if (gn >= N) continue;
      float v = acc[i][j] + (bias ? bias[gn] : 0.f);
      if (RELU) v = fmaxf(v, 0.f);
      C[(size_t)gm*N + gn] = v;
    }
  }
}

// ---------------- fused GEMM + add-LN: x = LN(x + A@W^T + bias)*g + b ----------------
// Block owns 64 full rows (N=224 fixed). 224 threads: rg=tid/28 (8 row-groups x 8 rows),
// cg=tid%28 (28 col-groups x 8 cols). Microtile 8x8. K must be multiple of 16.
__global__ __launch_bounds__(224) void gemmln_kernel(
    const float* __restrict__ A, const float* __restrict__ W,
    const float* __restrict__ bias, float* __restrict__ x,
    const float* __restrict__ g, const float* __restrict__ b, int K) {
  int row0 = blockIdx.x * 64;
  int tid = threadIdx.x;
  int rg = tid / 28, cg = tid % 28;
  __shared__ float As[16][68];
  __shared__ float Ws[16][284];     // 28 chunks of 8 cols, pitch 10 (bank-spread, 8B-aligned)
  __shared__ float red1[64][29];
  __shared__ float red2[64][29];
  __shared__ float mrr[64][2];
  float acc[8][8] = {};
  for (int k0 = 0; k0 < K; k0 += 16) {
    for (int idx = tid; idx < 64*16; idx += 224) {
      int m = idx >> 4, kk = idx & 15;
      int gm = row0 + m;
      As[kk][m] = (gm < TOK) ? A[(size_t)gm*K + k0 + kk] : 0.f;
    }
    for (int idx = tid; idx < 224*16; idx += 224) {
      int n = idx >> 4, kk = idx & 15;
      Ws[kk][(n >> 3)*10 + (n & 7)] = W[(size_t)n*K + k0 + kk];
    }
    __syncthreads();
#pragma unroll
    for (int kk = 0; kk < 16; ++kk) {
      float4 a0 = *(const float4*)&As[kk][rg*8];
      float4 a1 = *(const float4*)&As[kk][rg*8 + 4];
      const float* wr = &Ws[kk][cg*10];
      float2 w0 = *(const float2*)(wr);
      float2 w1 = *(const float2*)(wr + 2);
      float2 w2 = *(const float2*)(wr + 4);
      float2 w3 = *(const float2*)(wr + 6);
      float av[8] = {a0.x, a0.y, a0.z, a0.w, a1.x, a1.y, a1.z, a1.w};
      float wv[8] = {w0.x, w0.y, w1.x, w1.y, w2.x, w2.y, w3.x, w3.y};
#pragma unroll
      for (int i = 0; i < 8; ++i)
#pragma unroll
        for (int j = 0; j < 8; ++j)
          acc[i][j] += av[i] * wv[j];
    }
    __syncthreads();
  }
  // ---- LN tail ----
  int C0 = cg*8;
  float gv[8], bv[8], biasv[8];
#pragma unroll
  for (int j = 0; j < 8; ++j) { gv[j] = g[C0+j]; bv[j] = b[C0+j]; biasv[j] = bias[C0+j]; }
#pragma unroll
  for (int i = 0; i < 8; ++i) {
    int R = row0 + rg*8 + i;
    float ps = 0.f, ps2 = 0.f;
    if (R < TOK) {
      float4 xv0 = *(const float4*)(x + (size_t)R*E_ + C0);
      float4 xv1 = *(const float4*)(x + (size_t)R*E_ + C0 + 4);
      float xr[8] = {xv0.x, xv0.y, xv0.z, xv0.w, xv1.x, xv1.y, xv1.z, xv1.w};
#pragma unroll
      for (int j = 0; j < 8; ++j) {
        float v = xr[j] + acc[i][j] + biasv[j];
        acc[i][j] = v;
        ps += v; ps2 += v*v;
      }
    }
    red1[rg*8 + i][cg] = ps;
    red2[rg*8 + i][cg] = ps2;
  }
  __syncthreads();
  if (tid < 64) {
    float s1 = 0.f, s2 = 0.f;
    for (int c = 0; c < 28; ++c) { s1 += red1[tid][c]; s2 += red2[tid][c]; }
    float m = s1 / E_;
    float var = s2 / E_ - m*m;
    mrr[tid][0] = m;
    mrr[tid][1] = rsqrtf(var + 1e-5f);
  }
  __syncthreads();
#pragma unroll
  for (int i = 0; i < 8; ++i) {
    int lr = rg*8 + i;
    int R = row0 + lr;
    if (R >= TOK) continue;
    float m = mrr[lr][0], rs = mrr[lr][1];
    float o[8];
#pragma unroll
    for (int j = 0; j < 8; ++j) o[j] = (acc[i][j] - m) * rs * gv[j] + bv[j];
    *(float4*)(x + (size_t)R*E_ + C0)     = make_float4(o[0], o[1], o[2], o[3]);
    *(float4*)(x + (size_t)R*E_ + C0 + 4) = make_float4(o[4], o[5], o[6], o[7]);
  }
}

// ---------------- attention (one block per (b,h)) ----------------
__global__ __launch_bounds__(256) void attn_kernel(const float* __restrict__ qkv,
                                                   float* __restrict__ attn_o) {
  int bh = blockIdx.x;
  int b = bh / NH_, h = bh % NH_;
  __shared__ float Qs[NLOC][DH];
  __shared__ float Ks[NLOC][DH+1];
  __shared__ float Vs[NLOC][DH+1];
  __shared__ float Ps[4][NLOC];
  for (int i = threadIdx.x; i < NLOC*DH; i += 256) {
    int l = i / DH, d = i % DH;
    const float* base = qkv + ((size_t)(b*NLOC + l))*(3*E_);
    Qs[l][d] = base[h*DH + d];
    Ks[l][d] = base[E_ + h*DH + d];
    Vs[l][d] = base[2*E_ + h*DH + d];
  }
  __syncthreads();
  int wave = threadIdx.x >> 6, lane = threadIdx.x & 63;
  const float scale = 0.1889822365046136f;  // 1/sqrt(28)
  for (int l = wave; l < NLOC; l += 4) {
    int j0 = lane, j1 = lane + 64;
    bool has1 = (j1 < NLOC);
    int j1c = has1 ? j1 : 0;
    float s0 = 0.f, s1 = 0.f;
    for (int d = 0; d < DH; ++d) {
      float q = Qs[l][d];
      s0 += q * Ks[j0][d];
      s1 += q * Ks[j1c][d];
    }
    s0 *= scale; s1 *= scale;
    float m = fmaxf(s0, has1 ? s1 : -1e30f);
    for (int off = 32; off; off >>= 1) m = fmaxf(m, __shfl_xor(m, off));
    float p0 = __expf(s0 - m);
    float p1 = has1 ? __expf(s1 - m) : 0.f;
    float sum = p0 + p1;
    for (int off = 32; off; off >>= 1) sum += __shfl_xor(sum, off);
    float inv = 1.f / sum;
    Ps[wave][j0] = p0 * inv;
    if (has1) Ps[wave][j1] = p1 * inv;
    if (lane < DH) {
      float o = 0.f;
      for (int j = 0; j < NLOC; ++j) o += Ps[wave][j] * Vs[j][lane];
      attn_o[((size_t)(b*NLOC + l))*E_ + h*DH + lane] = o;
    }
  }
}

// ---------------- gather: seq[s][n][0:224]=x[b,locs_ix], [224:448]=msg_emb[b] ----------------
__global__ void gather_kernel(const float* __restrict__ x, const float* __restrict__ msg_emb,
                              const int* __restrict__ locs_ix, float* __restrict__ seq) {
  int idx = blockIdx.x*256 + threadIdx.x;
  if (idx >= MAXL*NCOL*(2*E_)) return;
  int k = idx % (2*E_);
  int rest = idx / (2*E_);
  int n = rest % NCOL, s = rest / NCOL;
  int b = n / NPOW;
  float v;
  if (k < E_) {
    int loc = locs_ix[n*MAXL + s];
    v = x[((size_t)(b*NLOC + loc))*E_ + k];
  } else {
    v = msg_emb[b*E_ + (k - E_)];
  }
  seq[idx] = v;
}

// ---------------- message embedding: msg_emb[b][n] = relu(msg_log[b,:] . msg_W[n,:] + msg_b[n]) ----
__global__ __launch_bounds__(256) void msgemb_kernel(
    const float* __restrict__ msg_log,  // [32][2000]
    const float* __restrict__ msg_W,    // [224][2000]
    const float* __restrict__ msg_b,
    float* __restrict__ msg_emb) {      // [32][224]
  int n = blockIdx.x;
  __shared__ float Wrow[MSGK];
  for (int i = threadIdx.x; i < MSGK; i += 256)
    Wrow[i] = msg_W[(size_t)n*MSGK + i];
  __syncthreads();
  int wave = threadIdx.x >> 6, lane = threadIdx.x & 63;
  int b0 = wave * 8;                    // 4 waves x 8 batch rows
  float acc[8] = {};
  for (int k = lane; k < MSGK; k += 64) {
    float w = Wrow[k];
#pragma unroll
    for (int r = 0; r < 8; ++r)
      acc[r] += w * msg_log[(size_t)(b0 + r)*MSGK + k];
  }
#pragma unroll
  for (int r = 0; r < 8; ++r) {
    float s = acc[r];
    for (int off = 32; off; off >>= 1) s += __shfl_xor(s, off);
    if (lane == 0) msg_emb[(size_t)(b0 + r)*E_ + n] = fmaxf(s + msg_b[n], 0.f);
  }
}

// ---------------- zero-fill dead (masked) dist rows ----------------
__global__ __launch_bounds__(256) void fill_dead_kernel(const int* __restrict__ locs_len,
                                                        float* __restrict__ out) {
  int gm = blockIdx.x;              // 0..NROW-1
  int n = gm / MAXL, s = gm % MAXL;
  if (s < locs_len[n]) return;
  float2* row = (float2*)(out + (size_t)gm*NACT);
  for (int i = threadIdx.x; i < NACT/2; i += 256)
    row[i] = make_float2(0.f, 0.f);
}

// ---------------- live-rows policy GEMM: 128x128x8 tile, 8x8 microtile (2x2 of 4x4) ----------------
#define PBM 128
#define PBN 128
#define PBK 8
__global__ __launch_bounds__(256) void pol_live_kernel(
    const float* __restrict__ hs, const float* __restrict__ pol_W,
    const float* __restrict__ pol_b, float* __restrict__ out) {
  int nlive = g_nlive;
  int row0 = blockIdx.y * PBM;
  if (row0 >= nlive) return;
  int col0 = blockIdx.x * PBN;
  __shared__ float As[PBK][PBM+4];
  __shared__ float Ws[PBK][PBN+4];
  __shared__ int rmap[PBM];
  int tid = threadIdx.x;
  for (int i = tid; i < PBM; i += 256) {
    int r = row0 + i;
    rmap[i] = (r < nlive) ? g_rowmap[r] : -1;
  }
  __syncthreads();
  int tx = tid & 15, ty = tid >> 4;
  int ms = tid >> 1, kq = tid & 1;      // staging: 128 rows x 2 half-k
  int gn_s = col0 + ms;
  float acc[2][2][4][4] = {};
  for (int k0 = 0; k0 < LSTM_H; k0 += PBK) {
    // ---- stage A (gathered live rows) and W ----
    {
      int gm = rmap[ms];
      float4 av = make_float4(0.f, 0.f, 0.f, 0.f);
      if (gm >= 0) av = *(const float4*)(hs + (size_t)gm*LSTM_H + k0 + kq*4);
      As[kq*4+0][ms] = av.x; As[kq*4+1][ms] = av.y;
      As[kq*4+2][ms] = av.z; As[kq*4+3][ms] = av.w;
      float4 wv = make_float4(0.f, 0.f, 0.f, 0.f);
      if (gn_s < NACT) wv = *(const float4*)(pol_W + (size_t)gn_s*LSTM_H + k0 + kq*4);
      Ws[kq*4+0][ms] = wv.x; Ws[kq*4+1][ms] = wv.y;
      Ws[kq*4+2][ms] = wv.z; Ws[kq*4+3][ms] = wv.w;
    }
    __syncthreads();
#pragma unroll
    for (int kk = 0; kk < PBK; ++kk) {
      float4 a0 = *(const float4*)&As[kk][ty*4];
      float4 a1 = *(const float4*)&As[kk][64 + ty*4];
      float4 w0 = *(const float4*)&Ws[kk][tx*4];
      float4 w1 = *(const float4*)&Ws[kk][64 + tx*4];
      float a_[2][4] = {{a0.x,a0.y,a0.z,a0.w},{a1.x,a1.y,a1.z,a1.w}};
      float w_[2][4] = {{w0.x,w0.y,w0.z,w0.w},{w1.x,w1.y,w1.z,w1.w}};
#pragma unroll
      for (int p = 0; p < 2; ++p)
#pragma unroll
        for (int q = 0; q < 2; ++q)
#pragma unroll
          for (int i = 0; i < 4; ++i)
#pragma unroll
            for (int j = 0; j < 4; ++j)
              acc[p][q][i][j] += a_[p][i] * w_[q][j];
    }
    __syncthreads();
  }
#pragma unroll
  for (int p = 0; p < 2; ++p)
#pragma unroll
    for (int i = 0; i < 4; ++i) {
      int rc = p*64 + ty*4 + i;
      if (row0 + rc >= nlive) continue;
      int gm = rmap[rc];
      float* orow = out + (size_t)gm*NACT;
#pragma unroll
      for (int q = 0; q < 2; ++q)
#pragma unroll
        for (int j = 0; j < 4; ++j) {
          int gn = col0 + q*64 + tx*4 + j;
          if (gn < NACT) orow[gn] = acc[p][q][i][j] + pol_b[gn];
        }
    }
}

// ---------------- two-layer LSTM v4: bf16 weights, 2 gates x 1 col per thread ----------------
__global__ __launch_bounds__(832) void lstm4_kernel(
    const float* __restrict__ gates0,   // [17*224][800] = seq@Wih0^T + bih0
    const uint4* __restrict__ WTH0,     // [25][800] bf16x8
    const uint4* __restrict__ WTH1,     // [50][800] bf16x8
    const float* __restrict__ bhh0,
    const float* __restrict__ bih1, const float* __restrict__ bhh1,
    float* __restrict__ hs) {           // [224][17][200]
  int n0 = blockIdx.x * 2;
  int tid = threadIdx.x;
  __shared__ float hx0[400];            // col0: [0:200]=h_l0, [200:400]=h_l1
  __shared__ float hx1[400];            // col1
  __shared__ float gar[2][800];
  for (int i = tid; i < 400; i += 832) { hx0[i] = 0.f; hx1[i] = 0.f; }
  int col = (tid >= 400) ? 1 : 0;
  int g2 = tid - col*400;               // 0..399
  const float* hxc = col ? hx1 : hx0;
  float bh0a = 0.f, bh0b = 0.f, b1a = 0.f, b1b = 0.f;
  if (tid < 800) {
    bh0a = bhh0[g2];        bh0b = bhh0[g2 + 400];
    b1a  = bih1[g2] + bhh1[g2];
    b1b  = bih1[g2 + 400] + bhh1[g2 + 400];
  }
  float c0 = 0.f, c1 = 0.f;             // cell state, threads 0..399
  __syncthreads();
  for (int s = 0; s < MAXL; ++s) {
    if (tid < 800) {
      const float* r = gates0 + ((size_t)s*NCOL + n0 + col)*800;
      float a0 = r[g2] + bh0a;
      float a1 = r[g2 + 400] + bh0b;
      const uint4* w0p = WTH0 + g2;
      const uint4* w1p = WTH0 + g2 + 400;
#pragma unroll 5
      for (int k8 = 0; k8 < 25; ++k8) {
        uint4 wv0 = w0p[(size_t)k8*800];
        uint4 wv1 = w1p[(size_t)k8*800];
        float4 ha = *(const float4*)&hxc[k8*8];
        float4 hA = *(const float4*)&hxc[k8*8 + 4];
        a0 += blo(wv0.x)*ha.x + bhi(wv0.x)*ha.y + blo(wv0.y)*ha.z + bhi(wv0.y)*ha.w
            + blo(wv0.z)*hA.x + bhi(wv0.z)*hA.y + blo(wv0.w)*hA.z + bhi(wv0.w)*hA.w;
        a1 += blo(wv1.x)*ha.x + bhi(wv1.x)*ha.y + blo(wv1.y)*ha.z + bhi(wv1.y)*ha.w
            + blo(wv1.z)*hA.x + bhi(wv1.z)*hA.y + blo(wv1.w)*hA.z + bhi(wv1.w)*hA.w;
      }
      gar[col][g2] = a0; gar[col][g2 + 400] = a1;
    }
    __syncthreads();
    if (tid < 400) {
      int cc = (tid < 200) ? 0 : 1;
      float* hx = cc ? hx1 : hx0;
      const float* gr = gar[cc];
      int j = tid - cc*200;
      float ig = sigm(gr[j]);
      float fg = sigm(gr[200 + j]);
      float gg = tanhf(gr[400 + j]);
      float og = sigm(gr[600 + j]);
      c0 = fg*c0 + ig*gg;
      hx[j] = og * tanhf(c0);
    }
    __syncthreads();
    if (tid < 800) {
      float a0 = b1a, a1 = b1b;
      const uint4* w0p = WTH1 + g2;
      const uint4* w1p = WTH1 + g2 + 400;
#pragma unroll 5
      for (int k8 = 0; k8 < 50; ++k8) {
        uint4 wv0 = w0p[(size_t)k8*800];
        uint4 wv1 = w1p[(size_t)k8*800];
        float4 ha = *(const float4*)&hxc[k8*8];
        float4 hA = *(const float4*)&hxc[k8*8 + 4];
        a0 += blo(wv0.x)*ha.x + bhi(wv0.x)*ha.y + blo(wv0.y)*ha.z + bhi(wv0.y)*ha.w
            + blo(wv0.z)*hA.x + bhi(wv0.z)*hA.y + blo(wv0.w)*hA.z + bhi(wv0.w)*hA.w;
        a1 += blo(wv1.x)*ha.x + bhi(wv1.x)*ha.y + blo(wv1.y)*ha.z + bhi(wv1.y)*ha.w
            + blo(wv1.z)*hA.x + bhi(wv1.z)*hA.y + blo(wv1.w)*hA.z + bhi(wv1.w)*hA.w;
      }
      gar[col][g2] = a0; gar[col][g2 + 400] = a1;
    }
    __syncthreads();
    if (tid < 400) {
      int cc = (tid < 200) ? 0 : 1;
      float* hx = cc ? hx1 : hx0;
      const float* gr = gar[cc];
      int j = tid - cc*200;
      float ig = sigm(gr[j]);
      float fg = sigm(gr[200 + j]);
      float gg = tanhf(gr[400 + j]);
      float og = sigm(gr[600 + j]);
      c1 = fg*c1 + ig*gg;
      float hh = og * tanhf(c1);
      hx[200 + j] = hh;
      hs[((size_t)(n0 + cc)*MAXL + s)*LSTM_H + j] = hh;
    }
    __syncthreads();
  }
}

// ---------------- lin1 split-K partials: P[sk][32][224] ----------------
__global__ __launch_bounds__(256) void lin1_partial_kernel(
    const float* __restrict__ x, const float* __restrict__ msg_emb,
    const float* __restrict__ W, float* __restrict__ P) {
  const int K = NLOC*E_ + E_;   // 18368
  const int chunk = 1148;       // 16 * 1148 = 18368
  int sk = blockIdx.z;
  int kb = sk*chunk, ke = kb + chunk;
  int col0 = blockIdx.x*32;
  __shared__ float As[16][36];
  __shared__ float Ws[16][36];
  int tid = threadIdx.x;
  int tx = tid & 15, ty = tid >> 4;
  float a00=0.f, a01=0.f, a10=0.f, a11=0.f;
  for (int k0 = kb; k0 < ke; k0 += 16) {
    for (int i = tid; i < 32*16; i += 256) {
      int m = i >> 4, kk = i & 15;
      int gk = k0 + kk;
      float v = 0.f;
      if (gk < ke) v = (gk < NLOC*E_) ? x[(size_t)m*(NLOC*E_) + gk] : msg_emb[m*E_ + gk - NLOC*E_];
      As[kk][m] = v;
      int n = col0 + m;
      Ws[kk][m] = (gk < ke) ? W[(size_t)n*K + gk] : 0.f;
    }
    __syncthreads();
#pragma unroll
    for (int kk = 0; kk < 16; ++kk) {
      float a0 = As[kk][ty*2], a1 = As[kk][ty*2+1];
      float w0 = Ws[kk][tx*2], w1 = Ws[kk][tx*2+1];
      a00 += a0*w0; a01 += a0*w1; a10 += a1*w0; a11 += a1*w1;
    }
    __syncthreads();
  }
  float* Pd = P + (size_t)sk*32*224;
  Pd[(ty*2  )*224 + col0 + tx*2  ] = a00;
  Pd[(ty*2  )*224 + col0 + tx*2+1] = a01;
  Pd[(ty*2+1)*224 + col0 + tx*2  ] = a10;
  Pd[(ty*2+1)*224 + col0 + tx*2+1] = a11;
}

// ---------------- value finalize: relu(sum P + b) @ lin2^T + b2 -> out f32 ----------------
__global__ __launch_bounds__(256) void value_finalize_kernel(
    const float* __restrict__ P, const float* __restrict__ lin1_b,
    const float* __restrict__ lin2_W, const float* __restrict__ lin2_b,
    float* __restrict__ out) {
  __shared__ float v1[32*224];
  for (int idx = threadIdx.x; idx < 32*224; idx += 256) {
    float s = 0.f;
    for (int sk = 0; sk < 16; ++sk) s += P[(size_t)sk*32*224 + idx];
    s += lin1_b[idx % 224];
    v1[idx] = fmaxf(s, 0.f);
  }
  __syncthreads();
  if (threadIdx.x < 32*NPOW) {
    int m = threadIdx.x / NPOW, q = threadIdx.x % NPOW;
    float s = lin2_b[q];
    for (int n = 0; n < E_; ++n) s += v1[m*224 + n] * lin2_W[q*E_ + n];
    out[m*NPOW + q] = s;
  }
}

extern "C" void kernel_launch(void* const* d_in, const int* in_sizes, int n_in,
                              void* d_out, int out_size, void* d_ws, size_t ws_size,
                              hipStream_t stream) {
  (void)in_sizes; (void)n_in; (void)out_size; (void)ws_size;
  const float* x_bo    = (const float*)d_in[0];
  const float* x_po    = (const float*)d_in[1];
  const float* msg_log = (const float*)d_in[2];
  const float* enc_W   = (const float*)d_in[3];
  const float* enc_b   = (const float*)d_in[4];
  const float* pos_bias= (const float*)d_in[5];
  const float* Wqkv    = (const float*)d_in[6];
  const float* bqkv    = (const float*)d_in[7];
  const float* Wo      = (const float*)d_in[8];
  const float* bo      = (const float*)d_in[9];
  const float* ln1_g   = (const float*)d_in[10];
  const float* ln1_b   = (const float*)d_in[11];
  const float* W1      = (const float*)d_in[12];
  const float* b1      = (const float*)d_in[13];
  const float* W2      = (const float*)d_in[14];
  const float* b2      = (const float*)d_in[15];
  const float* ln2_g   = (const float*)d_in[16];
  const float* ln2_b   = (const float*)d_in[17];
  const float* msg_W   = (const float*)d_in[18];
  const float* msg_b   = (const float*)d_in[19];
  const float* Wih0    = (const float*)d_in[20];
  const float* Whh0    = (const float*)d_in[21];
  const float* bih0    = (const float*)d_in[22];
  const float* bhh0    = (const float*)d_in[23];
  const float* Wih1    = (const float*)d_in[24];
  const float* Whh1    = (const float*)d_in[25];
  const float* bih1    = (const float*)d_in[26];
  const float* bhh1    = (const float*)d_in[27];
  const float* pol_W   = (const float*)d_in[28];
  const float* pol_b   = (const float*)d_in[29];
  const float* lin1_W  = (const float*)d_in[30];
  const float* lin1_b  = (const float*)d_in[31];
  const float* lin2_W  = (const float*)d_in[32];
  const float* lin2_b  = (const float*)d_in[33];
  const int*   locs_ix = (const int*)d_in[34];
  const int*   locs_len= (const int*)d_in[35];

  // ---- persistent scratch in ws (~5.9 MB) ----
  float* ws = (float*)d_ws;
  float* x        = ws;                    // 580608
  float* msg_emb  = ws + 580608;           // 7168
  float* P        = ws + 587776;           // 114688 -> ends 702464
  float* hs       = ws + 702464;           // 761600 -> ends 1464064

  // ---- large transient scratch inside d_out's f32 dist region (49.6M f32 slots,
  //      fully rewritten by fill_dead + pol_live at the end) ----
  float* os = (float*)d_out;
  float* qkv      = os;                    // 1741824
  float* attn_o   = os + 1741824;          // 580608
  float* ff1      = os + 2903040;          // 580608 -> ends 3483648
  float* seq      = os;                    // 1705984 (reuses qkv area after transformer)
  float* gates0   = os + 3483648;          // 3046400 -> ends 6530048
  uint4* WTH0     = (uint4*)(os + 6530048);   // 20000 uint4 = 80000 f32 -> ends 6610048
  uint4* WTH1     = (uint4*)(os + 6610048);   // 40000 uint4 = 160000 f32 -> ends 6770048
  float* out      = (float*)d_out;

  // ---- fused prep: encoder + bf16 weight pack + live-row scan ----
  prep_kernel<<<TOK + TRANSW_BLOCKS + 1, 256, 0, stream>>>(
      x_bo, x_po, enc_W, enc_b, pos_bias, x, Whh0, Wih1, Whh1, WTH0, WTH1, locs_len);

  // ---- transformer layers: 5 dispatches/layer (was 7) ----
  for (int l = 0; l < NLAYERS; ++l) {
    gemm_kernel<0><<<dim3(11, 41), 256, 0, stream>>>(
        x, Wqkv + (size_t)l*672*224, bqkv + l*672, qkv, TOK, 672, 224);
    attn_kernel<<<B_*NH_, 256, 0, stream>>>(qkv, attn_o);
    gemmln_kernel<<<(TOK + 63)/64, 224, 0, stream>>>(
        attn_o, Wo + (size_t)l*224*224, bo + l*224, x, ln1_g + l*224, ln1_b + l*224, 224);
    gemm_kernel<1><<<dim3(4, 41), 256, 0, stream>>>(
        x, W1 + (size_t)l*224*224, b1 + l*224, ff1, TOK, 224, 224);
    gemmln_kernel<<<(TOK + 63)/64, 224, 0, stream>>>(
        ff1, W2 + (size_t)l*224*224, b2 + l*224, x, ln2_g + l*224, ln2_b + l*224, 224);
  }

  // ---- message embedding: relu(msg_log @ msg_W^T + msg_b), 224 blocks ----
  msgemb_kernel<<<E_, 256, 0, stream>>>(msg_log, msg_W, msg_b, msg_emb);

  // ---- LSTM input sequence + hoisted input-gate GEMM ----
  gather_kernel<<<(MAXL*NCOL*448 + 255)/256, 256, 0, stream>>>(x, msg_emb, locs_ix, seq);
  gemm_kernel<0><<<dim3(13, 60), 256, 0, stream>>>(seq, Wih0, bih0, gates0, NROW, 800, 448);
  lstm4_kernel<<<NCOL/2, 832, 0, stream>>>(gates0, WTH0, WTH1, bhh0, bih1, bhh1, hs);

  // ---- policy head: zero dead rows (BW-bound) + GEMM only live rows ----
  fill_dead_kernel<<<NROW, 256, 0, stream>>>(locs_len, out);
  pol_live_kernel<<<dim3((NACT + PBN - 1)/PBN, (NROW + PBM - 1)/PBM), 256, 0, stream>>>(
      hs, pol_W, pol_b, out);

  // ---- value head ----
  lin1_partial_kernel<<<dim3(7, 1, 16), 256, 0, stream>>>(x, msg_emb, lin1_W, P);
  value_finalize_kernel<<<1, 256, 0, stream>>>(P, lin1_b, lin2_W, lin2_b, out + (size_t)DIST_SIZE);
}

// Round 9
// 2958.222 us; speedup vs baseline: 1.1483x; 1.1483x over previous
//
#include <hip/hip_runtime.h>
#include <hip/hip_bf16.h>
#include <math.h>

#define B_ 32
#define NLOC 81
#define SBO 35
#define SPO 40
#define E_ 224
#define NH_ 8
#define DH 28
#define NLAYERS 10
#define LSTM_H 200
#define NACT 13030
#define NPOW 7
#define MAXL 17
#define TOK (B_*NLOC)          // 2592
#define NCOL (B_*NPOW)         // 224
#define NROW (NCOL*MAXL)       // 3808
#define DIST_SIZE (B_*NPOW*MAXL*NACT)  // 49618240 f32 elements
#define MSGK 2000              // MSGLOG*MSGEMB
#define TRANSW_BLOCKS ((100*800 + 255)/256)   // 313

__device__ __forceinline__ float sigm(float x) { return 1.f / (1.f + __expf(-x)); }

// ---- device-global compaction state (graph-safe, no hipMalloc) ----
__device__ int g_rowmap[NROW];
__device__ int g_nlive;

// ---------------- prep: encoder + recurrent-weight pack (f32) + live-row scan ----------------
__global__ __launch_bounds__(256) void prep_kernel(
    const float* __restrict__ x_bo, const float* __restrict__ x_po,
    const float* __restrict__ enc_W, const float* __restrict__ enc_b,
    const float* __restrict__ pos_bias, float* __restrict__ x,
    const float* __restrict__ Whh0, const float* __restrict__ Wih1,
    const float* __restrict__ Whh1, float4* __restrict__ WTP0,
    float4* __restrict__ WTP1, const int* __restrict__ locs_len) {
  int bid = blockIdx.x;
  if (bid < TOK) {
    // ---- encoder: x = concat(x_bo,x_po) @ enc_W^T + enc_b + pos_bias ----
    int t = bid;
    int l = t % NLOC;
    __shared__ float in[SBO + SPO];
    if (threadIdx.x < SBO) in[threadIdx.x] = x_bo[(size_t)t*SBO + threadIdx.x];
    else if (threadIdx.x < SBO + SPO) in[threadIdx.x] = x_po[(size_t)t*SPO + threadIdx.x - SBO];
    __syncthreads();
    int e = threadIdx.x;
    if (e < E_) {
      float s = enc_b[e] + pos_bias[l*E_ + e];
      const float* w = enc_W + e*(SBO+SPO);
      for (int k = 0; k < SBO+SPO; ++k) s += in[k] * w[k];
      x[(size_t)t*E_ + e] = s;
    }
  } else if (bid < TOK + TRANSW_BLOCKS) {
    // ---- recurrent-weight transpose+pack (f32), as round-3 transw ----
    int idx = (bid - TOK)*256 + threadIdx.x;   // over 100*800
    if (idx >= 100*800) return;
    int k4 = idx / 800, g = idx % 800;
    const float* src = (k4 < 50) ? (Wih1 + (size_t)g*LSTM_H + 4*k4)
                                 : (Whh1 + (size_t)g*LSTM_H + 4*k4 - 200);
    WTP1[idx] = make_float4(src[0], src[1], src[2], src[3]);
    if (k4 < 50) {
      const float* s0 = Whh0 + (size_t)g*LSTM_H + 4*k4;
      WTP0[idx] = make_float4(s0[0], s0[1], s0[2], s0[3]);
    }
  } else {
    // ---- live-row compaction scan ----
    __shared__ int off[NCOL + 1];
    if (threadIdx.x == 0) {
      int acc = 0;
      for (int n = 0; n < NCOL; ++n) { off[n] = acc; acc += locs_len[n]; }
      off[NCOL] = acc;
      g_nlive = acc;
    }
    __syncthreads();
    for (int n = threadIdx.x; n < NCOL; n += 256) {
      int base = off[n], len = locs_len[n];
      for (int s = 0; s < len; ++s) g_rowmap[base + s] = n*MAXL + s;
    }
  }
}

// ---------------- generic GEMM: C[M,N] = A[M,K](f32) @ W[N,K]^T(f32) + bias ----------------
#define GBM 64
#define GBN 64
#define GBK 16
template<int RELU>
__global__ __launch_bounds__(256) void gemm_kernel(
    const float* __restrict__ A, const float* __restrict__ W,
    const float* __restrict__ bias, float* __restrict__ C,
    int M, int N, int K) {
  __shared__ float As[GBK][GBM+4];
  __shared__ float Ws[GBK][GBN+4];
  int tid = threadIdx.x;
  int tx = tid & 15, ty = tid >> 4;
  int row0 = blockIdx.y * GBM, col0 = blockIdx.x * GBN;
  float acc[4][4] = {};
  for (int k0 = 0; k0 < K; k0 += GBK) {
    for (int i = tid; i < GBM*GBK; i += 256) {
      int m = i >> 4, kk = i & 15;
      int gm = row0 + m, gk = k0 + kk;
      As[kk][m] = (gm < M && gk < K) ? A[(size_t)gm*K + gk] : 0.f;
    }
    for (int i = tid; i < GBN*GBK; i += 256) {
      int n = i >> 4, kk = i & 15;
      int gn = col0 + n, gk = k0 + kk;
      Ws[kk][n] = (gn < N && gk < K) ? W[(size_t)gn*K + gk] : 0.f;
    }
    __syncthreads();
#pragma unroll
    for (int kk = 0; kk < GBK; ++kk) {
      float4 av = *(const float4*)&As[kk][ty*4];
      float4 wv = *(const float4*)&Ws[kk][tx*4];
      float a_[4] = {av.x, av.y, av.z, av.w};
      float w_[4] = {wv.x, wv.y, wv.z, wv.w};
#pragma unroll
      for (int i = 0; i < 4; ++i)
#pragma unroll
        for (int j = 0; j < 4; ++j)
          acc[i][j] += a_[i] * w_[j];
    }
    __syncthreads();
  }
#pragma unroll
  for (int i = 0; i < 4; ++i) {
    int gm = row0 + ty*4 + i;
    if (gm >= M) continue;
#pragma unroll
    for (int j = 0; j < 4; ++j) {
      int gn = col0 + tx*4 + j;
      if (gn >= N) continue;
      float v = acc[i][j] + (bias ? bias[gn] : 0.f);
      if (RELU) v = fmaxf(v, 0.f);
      C[(size_t)gm*N + gn] = v;
    }
  }
}

// ---------------- attention (one block per (b,h)) ----------------
__global__ __launch_bounds__(256) void attn_kernel(const float* __restrict__ qkv,
                                                   float* __restrict__ attn_o) {
  int bh = blockIdx.x;
  int b = bh / NH_, h = bh % NH_;
  __shared__ float Qs[NLOC][DH];
  __shared__ float Ks[NLOC][DH+1];
  __shared__ float Vs[NLOC][DH+1];
  __shared__ float Ps[4][NLOC];
  for (int i = threadIdx.x; i < NLOC*DH; i += 256) {
    int l = i / DH, d = i % DH;
    const float* base = qkv + ((size_t)(b*NLOC + l))*(3*E_);
    Qs[l][d] = base[h*DH + d];
    Ks[l][d] = base[E_ + h*DH + d];
    Vs[l][d] = base[2*E_ + h*DH + d];
  }
  __syncthreads();
  int wave = threadIdx.x >> 6, lane = threadIdx.x & 63;
  const float scale = 0.1889822365046136f;  // 1/sqrt(28)
  for (int l = wave; l < NLOC; l += 4) {
    int j0 = lane, j1 = lane + 64;
    bool has1 = (j1 < NLOC);
    int j1c = has1 ? j1 : 0;
    float s0 = 0.f, s1 = 0.f;
    for (int d = 0; d < DH; ++d) {
      float q = Qs[l][d];
      s0 += q * Ks[j0][d];
      s1 += q * Ks[j1c][d];
    }
    s0 *= scale; s1 *= scale;
    float m = fmaxf(s0, has1 ? s1 : -1e30f);
    for (int off = 32; off; off >>= 1) m = fmaxf(m, __shfl_xor(m, off));
    float p0 = __expf(s0 - m);
    float p1 = has1 ? __expf(s1 - m) : 0.f;
    float sum = p0 + p1;
    for (int off = 32; off; off >>= 1) sum += __shfl_xor(sum, off);
    float inv = 1.f / sum;
    Ps[wave][j0] = p0 * inv;
    if (has1) Ps[wave][j1] = p1 * inv;
    if (lane < DH) {
      float o = 0.f;
      for (int j = 0; j < NLOC; ++j) o += Ps[wave][j] * Vs[j][lane];
      attn_o[((size_t)(b*NLOC + l))*E_ + h*DH + lane] = o;
    }
  }
}

// ---------------- x = LN(x + delta)*g + b (block per row, shuffle reductions) ----------------
__global__ __launch_bounds__(256) void addln_kernel(float* __restrict__ x,
                                                    const float* __restrict__ delta,
                                                    const float* __restrict__ g,
                                                    const float* __restrict__ bta) {
  int t = blockIdx.x;
  int e = threadIdx.x;
  int wave = e >> 6, lane = e & 63;
  __shared__ float ws4[4];
  float v = 0.f;
  if (e < E_) v = x[(size_t)t*E_ + e] + delta[(size_t)t*E_ + e];
  float s = v;
  for (int off = 32; off; off >>= 1) s += __shfl_xor(s, off);
  if (lane == 0) ws4[wave] = s;
  __syncthreads();
  float mean = (ws4[0] + ws4[1] + ws4[2] + ws4[3]) / E_;
  float d = (e < E_) ? (v - mean) : 0.f;
  float s2 = d * d;
  for (int off = 32; off; off >>= 1) s2 += __shfl_xor(s2, off);
  __syncthreads();
  if (lane == 0) ws4[wave] = s2;
  __syncthreads();
  float rstd = rsqrtf((ws4[0] + ws4[1] + ws4[2] + ws4[3]) / E_ + 1e-5f);
  if (e < E_) x[(size_t)t*E_ + e] = (v - mean) * rstd * g[e] + bta[e];
}

// ---------------- gather: seq[s][n][0:224]=x[b,locs_ix], [224:448]=msg_emb[b] ----------------
__global__ void gather_kernel(const float* __restrict__ x, const float* __restrict__ msg_emb,
                              const int* __restrict__ locs_ix, float* __restrict__ seq) {
  int idx = blockIdx.x*256 + threadIdx.x;
  if (idx >= MAXL*NCOL*(2*E_)) return;
  int k = idx % (2*E_);
  int rest = idx / (2*E_);
  int n = rest % NCOL, s = rest / NCOL;
  int b = n / NPOW;
  float v;
  if (k < E_) {
    int loc = locs_ix[n*MAXL + s];
    v = x[((size_t)(b*NLOC + loc))*E_ + k];
  } else {
    v = msg_emb[b*E_ + (k - E_)];
  }
  seq[idx] = v;
}

// ---------------- message embedding: msg_emb[b][n] = relu(msg_log[b,:] . msg_W[n,:] + msg_b[n]) ----
__global__ __launch_bounds__(256) void msgemb_kernel(
    const float* __restrict__ msg_log,  // [32][2000]
    const float* __restrict__ msg_W,    // [224][2000]
    const float* __restrict__ msg_b,
    float* __restrict__ msg_emb) {      // [32][224]
  int n = blockIdx.x;
  __shared__ float Wrow[MSGK];
  for (int i = threadIdx.x; i < MSGK; i += 256)
    Wrow[i] = msg_W[(size_t)n*MSGK + i];
  __syncthreads();
  int wave = threadIdx.x >> 6, lane = threadIdx.x & 63;
  int b0 = wave * 8;                    // 4 waves x 8 batch rows
  float acc[8] = {};
  for (int k = lane; k < MSGK; k += 64) {
    float w = Wrow[k];
#pragma unroll
    for (int r = 0; r < 8; ++r)
      acc[r] += w * msg_log[(size_t)(b0 + r)*MSGK + k];
  }
#pragma unroll
  for (int r = 0; r < 8; ++r) {
    float s = acc[r];
    for (int off = 32; off; off >>= 1) s += __shfl_xor(s, off);
    if (lane == 0) msg_emb[(size_t)(b0 + r)*E_ + n] = fmaxf(s + msg_b[n], 0.f);
  }
}

// ---------------- zero-fill dead (masked) dist rows ----------------
__global__ __launch_bounds__(256) void fill_dead_kernel(const int* __restrict__ locs_len,
                                                        float* __restrict__ out) {
  int gm = blockIdx.x;              // 0..NROW-1
  int n = gm / MAXL, s = gm % MAXL;
  if (s < locs_len[n]) return;
  float2* row = (float2*)(out + (size_t)gm*NACT);
  for (int i = threadIdx.x; i < NACT/2; i += 256)
    row[i] = make_float2(0.f, 0.f);
}

// ---------------- live-rows policy GEMM: 128x128x8 tile, 8x8 microtile (2x2 of 4x4) ----------------
#define PBM 128
#define PBN 128
#define PBK 8
__global__ __launch_bounds__(256) void pol_live_kernel(
    const float* __restrict__ hs, const float* __restrict__ pol_W,
    const float* __restrict__ pol_b, float* __restrict__ out) {
  int nlive = g_nlive;
  int row0 = blockIdx.y * PBM;
  if (row0 >= nlive) return;
  int col0 = blockIdx.x * PBN;
  __shared__ float As[PBK][PBM+4];
  __shared__ float Ws[PBK][PBN+4];
  __shared__ int rmap[PBM];
  int tid = threadIdx.x;
  for (int i = tid; i < PBM; i += 256) {
    int r = row0 + i;
    rmap[i] = (r < nlive) ? g_rowmap[r] : -1;
  }
  __syncthreads();
  int tx = tid & 15, ty = tid >> 4;
  int ms = tid >> 1, kq = tid & 1;      // staging: 128 rows x 2 half-k
  int gn_s = col0 + ms;
  float acc[2][2][4][4] = {};
  for (int k0 = 0; k0 < LSTM_H; k0 += PBK) {
    // ---- stage A (gathered live rows) and W ----
    {
      int gm = rmap[ms];
      float4 av = make_float4(0.f, 0.f, 0.f, 0.f);
      if (gm >= 0) av = *(const float4*)(hs + (size_t)gm*LSTM_H + k0 + kq*4);
      As[kq*4+0][ms] = av.x; As[kq*4+1][ms] = av.y;
      As[kq*4+2][ms] = av.z; As[kq*4+3][ms] = av.w;
      float4 wv = make_float4(0.f, 0.f, 0.f, 0.f);
      if (gn_s < NACT) wv = *(const float4*)(pol_W + (size_t)gn_s*LSTM_H + k0 + kq*4);
      Ws[kq*4+0][ms] = wv.x; Ws[kq*4+1][ms] = wv.y;
      Ws[kq*4+2][ms] = wv.z; Ws[kq*4+3][ms] = wv.w;
    }
    __syncthreads();
#pragma unroll
    for (int kk = 0; kk < PBK; ++kk) {
      float4 a0 = *(const float4*)&As[kk][ty*4];
      float4 a1 = *(const float4*)&As[kk][64 + ty*4];
      float4 w0 = *(const float4*)&Ws[kk][tx*4];
      float4 w1 = *(const float4*)&Ws[kk][64 + tx*4];
      float a_[2][4] = {{a0.x,a0.y,a0.z,a0.w},{a1.x,a1.y,a1.z,a1.w}};
      float w_[2][4] = {{w0.x,w0.y,w0.z,w0.w},{w1.x,w1.y,w1.z,w1.w}};
#pragma unroll
      for (int p = 0; p < 2; ++p)
#pragma unroll
        for (int q = 0; q < 2; ++q)
#pragma unroll
          for (int i = 0; i < 4; ++i)
#pragma unroll
            for (int j = 0; j < 4; ++j)
              acc[p][q][i][j] += a_[p][i] * w_[q][j];
    }
    __syncthreads();
  }
#pragma unroll
  for (int p = 0; p < 2; ++p)
#pragma unroll
    for (int i = 0; i < 4; ++i) {
      int rc = p*64 + ty*4 + i;
      if (row0 + rc >= nlive) continue;
      int gm = rmap[rc];
      float* orow = out + (size_t)gm*NACT;
#pragma unroll
      for (int q = 0; q < 2; ++q)
#pragma unroll
        for (int j = 0; j < 4; ++j) {
          int gn = col0 + q*64 + tx*4 + j;
          if (gn < NACT) orow[gn] = acc[p][q][i][j] + pol_b[gn];
        }
    }
}

// ---------------- two-layer LSTM v5: f32 weights, ONE column per block (224 blocks) ----------
// Halves per-block VALU and LDS vs v2 while keeping the weight stream; serial-sum model
// predicts ~26K cyc/step vs v2's measured 45.7K.
__global__ __launch_bounds__(832) void lstm5_kernel(
    const float* __restrict__ gates0,   // [17*224][800] = seq@Wih0^T + bih0
    const float4* __restrict__ WTP0,    // [50][800]
    const float4* __restrict__ WTP1,    // [100][800]
    const float* __restrict__ bhh0,
    const float* __restrict__ bih1, const float* __restrict__ bhh1,
    float* __restrict__ hs) {           // [224][17][200]
  int n = blockIdx.x;
  int tid = threadIdx.x;
  __shared__ float hx[400];             // [0:200]=h_l0, [200:400]=h_l1
  __shared__ float gar[800];
  for (int i = tid; i < 400; i += 832) hx[i] = 0.f;
  float bh0 = 0.f, b1s = 0.f;
  if (tid < 800) { bh0 = bhh0[tid]; b1s = bih1[tid] + bhh1[tid]; }
  float c0 = 0.f, c1 = 0.f;             // cell state, threads 0..199
  __syncthreads();
  for (int s = 0; s < MAXL; ++s) {
    // ---- layer0 gates: a = gates0_row + bhh0 + h0 @ Whh0^T ----
    if (tid < 800) {
      float a = gates0[((size_t)s*NCOL + n)*800 + tid] + bh0;
      const float4* w = WTP0 + tid;
#pragma unroll 5
      for (int k4 = 0; k4 < 50; ++k4) {
        float4 wv = w[(size_t)k4*800];
        float4 ha = *(const float4*)&hx[k4*4];
        a += ha.x*wv.x + ha.y*wv.y + ha.z*wv.z + ha.w*wv.w;
      }
      gar[tid] = a;
    }
    __syncthreads();
    // ---- layer0 update ----
    if (tid < 200) {
      float ig = sigm(gar[tid]);
      float fg = sigm(gar[200 + tid]);
      float gg = tanhf(gar[400 + tid]);
      float og = sigm(gar[600 + tid]);
      c0 = fg*c0 + ig*gg;
      hx[tid] = og * tanhf(c0);
    }
    __syncthreads();
    // ---- layer1 gates: a = bih1+bhh1 + h0 @ Wih1^T + h1 @ Whh1^T ----
    if (tid < 800) {
      float a = b1s;
      const float4* w = WTP1 + tid;
#pragma unroll 5
      for (int k4 = 0; k4 < 100; ++k4) {
        float4 wv = w[(size_t)k4*800];
        float4 ha = *(const float4*)&hx[k4*4];
        a += ha.x*wv.x + ha.y*wv.y + ha.z*wv.z + ha.w*wv.w;
      }
      gar[tid] = a;
    }
    __syncthreads();
    // ---- layer1 update + emit hs ----
    if (tid < 200) {
      float ig = sigm(gar[tid]);
      float fg = sigm(gar[200 + tid]);
      float gg = tanhf(gar[400 + tid]);
      float og = sigm(gar[600 + tid]);
      c1 = fg*c1 + ig*gg;
      float hh = og * tanhf(c1);
      hx[200 + tid] = hh;
      hs[((size_t)n*MAXL + s)*LSTM_H + tid] = hh;
    }
    __syncthreads();
  }
}

// ---------------- lin1 split-K partials: P[sk][32][224] ----------------
__global__ __launch_bounds__(256) void lin1_partial_kernel(
    const float* __restrict__ x, const float* __restrict__ msg_emb,
    const float* __restrict__ W, float* __restrict__ P) {
  const int K = NLOC*E_ + E_;   // 18368
  const int chunk = 1148;       // 16 * 1148 = 18368
  int sk = blockIdx.z;
  int kb = sk*chunk, ke = kb + chunk;
  int col0 = blockIdx.x*32;
  __shared__ float As[16][36];
  __shared__ float Ws[16][36];
  int tid = threadIdx.x;
  int tx = tid & 15, ty = tid >> 4;
  float a00=0.f, a01=0.f, a10=0.f, a11=0.f;
  for (int k0 = kb; k0 < ke; k0 += 16) {
    for (int i = tid; i < 32*16; i += 256) {
      int m = i >> 4, kk = i & 15;
      int gk = k0 + kk;
      float v = 0.f;
      if (gk < ke) v = (gk < NLOC*E_) ? x[(size_t)m*(NLOC*E_) + gk] : msg_emb[m*E_ + gk - NLOC*E_];
      As[kk][m] = v;
      int n = col0 + m;
      Ws[kk][m] = (gk < ke) ? W[(size_t)n*K + gk] : 0.f;
    }
    __syncthreads();
#pragma unroll
    for (int kk = 0; kk < 16; ++kk) {
      float a0 = As[kk][ty*2], a1 = As[kk][ty*2+1];
      float w0 = Ws[kk][tx*2], w1 = Ws[kk][tx*2+1];
      a00 += a0*w0; a01 += a0*w1; a10 += a1*w0; a11 += a1*w1;
    }
    __syncthreads();
  }
  float* Pd = P + (size_t)sk*32*224;
  Pd[(ty*2  )*224 + col0 + tx*2  ] = a00;
  Pd[(ty*2  )*224 + col0 + tx*2+1] = a01;
  Pd[(ty*2+1)*224 + col0 + tx*2  ] = a10;
  Pd[(ty*2+1)*224 + col0 + tx*2+1] = a11;
}

// ---------------- value finalize: relu(sum P + b) @ lin2^T + b2 -> out f32 ----------------
__global__ __launch_bounds__(256) void value_finalize_kernel(
    const float* __restrict__ P, const float* __restrict__ lin1_b,
    const float* __restrict__ lin2_W, const float* __restrict__ lin2_b,
    float* __restrict__ out) {
  __shared__ float v1[32*224];
  for (int idx = threadIdx.x; idx < 32*224; idx += 256) {
    float s = 0.f;
    for (int sk = 0; sk < 16; ++sk) s += P[(size_t)sk*32*224 + idx];
    s += lin1_b[idx % 224];
    v1[idx] = fmaxf(s, 0.f);
  }
  __syncthreads();
  if (threadIdx.x < 32*NPOW) {
    int m = threadIdx.x / NPOW, q = threadIdx.x % NPOW;
    float s = lin2_b[q];
    for (int n = 0; n < E_; ++n) s += v1[m*224 + n] * lin2_W[q*E_ + n];
    out[m*NPOW + q] = s;
  }
}

extern "C" void kernel_launch(void* const* d_in, const int* in_sizes, int n_in,
                              void* d_out, int out_size, void* d_ws, size_t ws_size,
                              hipStream_t stream) {
  (void)in_sizes; (void)n_in; (void)out_size; (void)ws_size;
  const float* x_bo    = (const float*)d_in[0];
  const float* x_po    = (const float*)d_in[1];
  const float* msg_log = (const float*)d_in[2];
  const float* enc_W   = (const float*)d_in[3];
  const float* enc_b   = (const float*)d_in[4];
  const float* pos_bias= (const float*)d_in[5];
  const float* Wqkv    = (const float*)d_in[6];
  const float* bqkv    = (const float*)d_in[7];
  const float* Wo      = (const float*)d_in[8];
  const float* bo      = (const float*)d_in[9];
  const float* ln1_g   = (const float*)d_in[10];
  const float* ln1_b   = (const float*)d_in[11];
  const float* W1      = (const float*)d_in[12];
  const float* b1      = (const float*)d_in[13];
  const float* W2      = (const float*)d_in[14];
  const float* b2      = (const float*)d_in[15];
  const float* ln2_g   = (const float*)d_in[16];
  const float* ln2_b   = (const float*)d_in[17];
  const float* msg_W   = (const float*)d_in[18];
  const float* msg_b   = (const float*)d_in[19];
  const float* Wih0    = (const float*)d_in[20];
  const float* Whh0    = (const float*)d_in[21];
  const float* bih0    = (const float*)d_in[22];
  const float* bhh0    = (const float*)d_in[23];
  const float* Wih1    = (const float*)d_in[24];
  const float* Whh1    = (const float*)d_in[25];
  const float* bih1    = (const float*)d_in[26];
  const float* bhh1    = (const float*)d_in[27];
  const float* pol_W   = (const float*)d_in[28];
  const float* pol_b   = (const float*)d_in[29];
  const float* lin1_W  = (const float*)d_in[30];
  const float* lin1_b  = (const float*)d_in[31];
  const float* lin2_W  = (const float*)d_in[32];
  const float* lin2_b  = (const float*)d_in[33];
  const int*   locs_ix = (const int*)d_in[34];
  const int*   locs_len= (const int*)d_in[35];

  // ---- persistent scratch in ws (~5.9 MB) ----
  float* ws = (float*)d_ws;
  float* x        = ws;                    // 580608
  float* msg_emb  = ws + 580608;           // 7168
  float* P        = ws + 587776;           // 114688 -> ends 702464
  float* hs       = ws + 702464;           // 761600 -> ends 1464064

  // ---- large transient scratch inside d_out's f32 dist region (49.6M f32 slots,
  //      fully rewritten by fill_dead + pol_live at the end) ----
  float* os = (float*)d_out;
  float* qkv      = os;                    // 1741824
  float* attn_o   = os + 1741824;          // 580608
  float* tmp      = os + 2322432;          // 580608
  float* ff1      = os + 2903040;          // 580608 -> ends 3483648
  float* seq      = os;                    // 1705984 (reuses qkv area after transformer)
  float* gates0   = os + 3483648;          // 3046400 -> ends 6530048
  float4* WTP0    = (float4*)(os + 6530048);  // 160000 f32 -> ends 6690048
  float4* WTP1    = (float4*)(os + 6690048);  // 320000 f32 -> ends 7010048 (< 49618240)
  float* out      = (float*)d_out;

  // ---- fused prep: encoder + f32 weight pack + live-row scan (independent blocks) ----
  prep_kernel<<<TOK + TRANSW_BLOCKS + 1, 256, 0, stream>>>(
      x_bo, x_po, enc_W, enc_b, pos_bias, x, Whh0, Wih1, Whh1, WTP0, WTP1, locs_len);

  // ---- transformer layers ----
  for (int l = 0; l < NLAYERS; ++l) {
    gemm_kernel<0><<<dim3(11, 41), 256, 0, stream>>>(
        x, Wqkv + (size_t)l*672*224, bqkv + l*672, qkv, TOK, 672, 224);
    attn_kernel<<<B_*NH_, 256, 0, stream>>>(qkv, attn_o);
    gemm_kernel<0><<<dim3(4, 41), 256, 0, stream>>>(
        attn_o, Wo + (size_t)l*224*224, bo + l*224, tmp, TOK, 224, 224);
    addln_kernel<<<TOK, 256, 0, stream>>>(x, tmp, ln1_g + l*224, ln1_b + l*224);
    gemm_kernel<1><<<dim3(4, 41), 256, 0, stream>>>(
        x, W1 + (size_t)l*224*224, b1 + l*224, ff1, TOK, 224, 224);
    gemm_kernel<0><<<dim3(4, 41), 256, 0, stream>>>(
        ff1, W2 + (size_t)l*224*224, b2 + l*224, tmp, TOK, 224, 224);
    addln_kernel<<<TOK, 256, 0, stream>>>(x, tmp, ln2_g + l*224, ln2_b + l*224);
  }

  // ---- message embedding: relu(msg_log @ msg_W^T + msg_b), 224 blocks ----
  msgemb_kernel<<<E_, 256, 0, stream>>>(msg_log, msg_W, msg_b, msg_emb);

  // ---- LSTM input sequence + hoisted input-gate GEMM ----
  gather_kernel<<<(MAXL*NCOL*448 + 255)/256, 256, 0, stream>>>(x, msg_emb, locs_ix, seq);
  gemm_kernel<0><<<dim3(13, 60), 256, 0, stream>>>(seq, Wih0, bih0, gates0, NROW, 800, 448);
  lstm5_kernel<<<NCOL, 832, 0, stream>>>(gates0, WTP0, WTP1, bhh0, bih1, bhh1, hs);

  // ---- policy head: zero dead rows (BW-bound) + GEMM only live rows ----
  fill_dead_kernel<<<NROW, 256, 0, stream>>>(locs_len, out);
  pol_live_kernel<<<dim3((NACT + PBN - 1)/PBN, (NROW + PBM - 1)/PBM), 256, 0, stream>>>(
      hs, pol_W, pol_b, out);

  // ---- value head ----
  lin1_partial_kernel<<<dim3(7, 1, 16), 256, 0, stream>>>(x, msg_emb, lin1_W, P);
  value_finalize_kernel<<<1, 256, 0, stream>>>(P, lin1_b, lin2_W, lin2_b, out + (size_t)DIST_SIZE);
}

// Round 10
// 2831.566 us; speedup vs baseline: 1.1996x; 1.0447x over previous
//
#include <hip/hip_runtime.h>
#include <hip/hip_bf16.h>
#include <math.h>

#define B_ 32
#define NLOC 81
#define SBO 35
#define SPO 40
#define E_ 224
#define NH_ 8
#define DH 28
#define NLAYERS 10
#define LSTM_H 200
#define NACT 13030
#define NPOW 7
#define MAXL 17
#define TOK (B_*NLOC)          // 2592
#define NCOL (B_*NPOW)         // 224
#define NROW (NCOL*MAXL)       // 3808
#define DIST_SIZE (B_*NPOW*MAXL*NACT)  // 49618240 f32 elements
#define MSGK 2000              // MSGLOG*MSGEMB
#define TRANSW_BLOCKS ((100*800 + 255)/256)   // 313

__device__ __forceinline__ float sigm(float x) { return 1.f / (1.f + __expf(-x)); }

// ---- device-global compaction state (graph-safe, no hipMalloc) ----
__device__ int g_rowmap[NROW];
__device__ int g_nlive;

// ---------------- prep: encoder + recurrent-weight pack (f32) + live-row scan ----------------
__global__ __launch_bounds__(256) void prep_kernel(
    const float* __restrict__ x_bo, const float* __restrict__ x_po,
    const float* __restrict__ enc_W, const float* __restrict__ enc_b,
    const float* __restrict__ pos_bias, float* __restrict__ x,
    const float* __restrict__ Whh0, const float* __restrict__ Wih1,
    const float* __restrict__ Whh1, float4* __restrict__ WTP0,
    float4* __restrict__ WTP1, const int* __restrict__ locs_len) {
  int bid = blockIdx.x;
  if (bid < TOK) {
    // ---- encoder: x = concat(x_bo,x_po) @ enc_W^T + enc_b + pos_bias ----
    int t = bid;
    int l = t % NLOC;
    __shared__ float in[SBO + SPO];
    if (threadIdx.x < SBO) in[threadIdx.x] = x_bo[(size_t)t*SBO + threadIdx.x];
    else if (threadIdx.x < SBO + SPO) in[threadIdx.x] = x_po[(size_t)t*SPO + threadIdx.x - SBO];
    __syncthreads();
    int e = threadIdx.x;
    if (e < E_) {
      float s = enc_b[e] + pos_bias[l*E_ + e];
      const float* w = enc_W + e*(SBO+SPO);
      for (int k = 0; k < SBO+SPO; ++k) s += in[k] * w[k];
      x[(size_t)t*E_ + e] = s;
    }
  } else if (bid < TOK + TRANSW_BLOCKS) {
    // ---- recurrent-weight transpose+pack (f32) ----
    int idx = (bid - TOK)*256 + threadIdx.x;   // over 100*800
    if (idx >= 100*800) return;
    int k4 = idx / 800, g = idx % 800;
    const float* src = (k4 < 50) ? (Wih1 + (size_t)g*LSTM_H + 4*k4)
                                 : (Whh1 + (size_t)g*LSTM_H + 4*k4 - 200);
    WTP1[idx] = make_float4(src[0], src[1], src[2], src[3]);
    if (k4 < 50) {
      const float* s0 = Whh0 + (size_t)g*LSTM_H + 4*k4;
      WTP0[idx] = make_float4(s0[0], s0[1], s0[2], s0[3]);
    }
  } else {
    // ---- live-row compaction scan ----
    __shared__ int off[NCOL + 1];
    if (threadIdx.x == 0) {
      int acc = 0;
      for (int n = 0; n < NCOL; ++n) { off[n] = acc; acc += locs_len[n]; }
      off[NCOL] = acc;
      g_nlive = acc;
    }
    __syncthreads();
    for (int n = threadIdx.x; n < NCOL; n += 256) {
      int base = off[n], len = locs_len[n];
      for (int s = 0; s < len; ++s) g_rowmap[base + s] = n*MAXL + s;
    }
  }
}

// ---------------- generic GEMM: C[M,N] = A[M,K](f32) @ W[N,K]^T(f32) + bias ----------------
#define GBM 64
#define GBN 64
#define GBK 16
template<int RELU>
__global__ __launch_bounds__(256) void gemm_kernel(
    const float* __restrict__ A, const float* __restrict__ W,
    const float* __restrict__ bias, float* __restrict__ C,
    int M, int N, int K) {
  __shared__ float As[GBK][GBM+4];
  __shared__ float Ws[GBK][GBN+4];
  int tid = threadIdx.x;
  int tx = tid & 15, ty = tid >> 4;
  int row0 = blockIdx.y * GBM, col0 = blockIdx.x * GBN;
  float acc[4][4] = {};
  for (int k0 = 0; k0 < K; k0 += GBK) {
    for (int i = tid; i < GBM*GBK; i += 256) {
      int m = i >> 4, kk = i & 15;
      int gm = row0 + m, gk = k0 + kk;
      As[kk][m] = (gm < M && gk < K) ? A[(size_t)gm*K + gk] : 0.f;
    }
    for (int i = tid; i < GBN*GBK; i += 256) {
      int n = i >> 4, kk = i & 15;
      int gn = col0 + n, gk = k0 + kk;
      Ws[kk][n] = (gn < N && gk < K) ? W[(size_t)gn*K + gk] : 0.f;
    }
    __syncthreads();
#pragma unroll
    for (int kk = 0; kk < GBK; ++kk) {
      float4 av = *(const float4*)&As[kk][ty*4];
      float4 wv = *(const float4*)&Ws[kk][tx*4];
      float a_[4] = {av.x, av.y, av.z, av.w};
      float w_[4] = {wv.x, wv.y, wv.z, wv.w};
#pragma unroll
      for (int i = 0; i < 4; ++i)
#pragma unroll
        for (int j = 0; j < 4; ++j)
          acc[i][j] += a_[i] * w_[j];
    }
    __syncthreads();
  }
#pragma unroll
  for (int i = 0; i < 4; ++i) {
    int gm = row0 + ty*4 + i;
    if (gm >= M) continue;
#pragma unroll
    for (int j = 0; j < 4; ++j) {
      int gn = col0 + tx*4 + j;
      if (gn >= N) continue;
      float v = acc[i][j] + (bias ? bias[gn] : 0.f);
      if (RELU) v = fmaxf(v, 0.f);
      C[(size_t)gm*N + gn] = v;
    }
  }
}

// ---------------- attention v2: 4 blocks per (b,h), split-half PV ----------------
// grid = B_*NH_*4. Block handles l = {gw, gw+16, ...} where gw = wave + 4*chunk.
// PV: lanes 0-31 accumulate j=0..40, lanes 32-63 j=41..80 (dd = lane&31), combine shfl_xor(32).
__global__ __launch_bounds__(256) void attn_kernel(const float* __restrict__ qkv,
                                                   float* __restrict__ attn_o) {
  int bh = blockIdx.x >> 2;
  int chunk = blockIdx.x & 3;
  int b = bh / NH_, h = bh % NH_;
  __shared__ float Qs[NLOC][DH];
  __shared__ float Ks[NLOC][DH+1];
  __shared__ float Vs[NLOC][DH+1];
  __shared__ float Ps[4][NLOC];
  for (int i = threadIdx.x; i < NLOC*DH; i += 256) {
    int l = i / DH, d = i % DH;
    const float* base = qkv + ((size_t)(b*NLOC + l))*(3*E_);
    Qs[l][d] = base[h*DH + d];
    Ks[l][d] = base[E_ + h*DH + d];
    Vs[l][d] = base[2*E_ + h*DH + d];
  }
  __syncthreads();
  int wave = threadIdx.x >> 6, lane = threadIdx.x & 63;
  int half = lane >> 5, dd = lane & 31;
  const float scale = 0.1889822365046136f;  // 1/sqrt(28)
  for (int l = wave + chunk*4; l < NLOC; l += 16) {
    int j0 = lane, j1 = lane + 64;
    bool has1 = (j1 < NLOC);
    int j1c = has1 ? j1 : 0;
    float s0 = 0.f, s1 = 0.f;
    for (int d = 0; d < DH; ++d) {
      float q = Qs[l][d];
      s0 += q * Ks[j0][d];
      s1 += q * Ks[j1c][d];
    }
    s0 *= scale; s1 *= scale;
    float m = fmaxf(s0, has1 ? s1 : -1e30f);
    for (int off = 32; off; off >>= 1) m = fmaxf(m, __shfl_xor(m, off));
    float p0 = __expf(s0 - m);
    float p1 = has1 ? __expf(s1 - m) : 0.f;
    float sum = p0 + p1;
    for (int off = 32; off; off >>= 1) sum += __shfl_xor(sum, off);
    float inv = 1.f / sum;
    Ps[wave][j0] = p0 * inv;
    if (has1) Ps[wave][j1] = p1 * inv;
    // ---- PV: half 0 sums j=0..40, half 1 sums j=41..80; dd = lane&31 is the d index ----
    float o = 0.f;
    int jend = half ? NLOC : 41;
    bool dok = (dd < DH);
    for (int j = half*41; j < jend; ++j) {
      float p = Ps[wave][j];
      float vv = dok ? Vs[j][dd] : 0.f;
      o += p * vv;
    }
    o += __shfl_xor(o, 32);
    if (lane < DH)
      attn_o[((size_t)(b*NLOC + l))*E_ + h*DH + lane] = o;
  }
}

// ---------------- x = LN(x + delta)*g + b (block per row, shuffle reductions) ----------------
__global__ __launch_bounds__(256) void addln_kernel(float* __restrict__ x,
                                                    const float* __restrict__ delta,
                                                    const float* __restrict__ g,
                                                    const float* __restrict__ bta) {
  int t = blockIdx.x;
  int e = threadIdx.x;
  int wave = e >> 6, lane = e & 63;
  __shared__ float ws4[4];
  float v = 0.f;
  if (e < E_) v = x[(size_t)t*E_ + e] + delta[(size_t)t*E_ + e];
  float s = v;
  for (int off = 32; off; off >>= 1) s += __shfl_xor(s, off);
  if (lane == 0) ws4[wave] = s;
  __syncthreads();
  float mean = (ws4[0] + ws4[1] + ws4[2] + ws4[3]) / E_;
  float d = (e < E_) ? (v - mean) : 0.f;
  float s2 = d * d;
  for (int off = 32; off; off >>= 1) s2 += __shfl_xor(s2, off);
  __syncthreads();
  if (lane == 0) ws4[wave] = s2;
  __syncthreads();
  float rstd = rsqrtf((ws4[0] + ws4[1] + ws4[2] + ws4[3]) / E_ + 1e-5f);
  if (e < E_) x[(size_t)t*E_ + e] = (v - mean) * rstd * g[e] + bta[e];
}

// ---------------- gather: seq[s][n][0:224]=x[b,locs_ix], [224:448]=msg_emb[b] ----------------
__global__ void gather_kernel(const float* __restrict__ x, const float* __restrict__ msg_emb,
                              const int* __restrict__ locs_ix, float* __restrict__ seq) {
  int idx = blockIdx.x*256 + threadIdx.x;
  if (idx >= MAXL*NCOL*(2*E_)) return;
  int k = idx % (2*E_);
  int rest = idx / (2*E_);
  int n = rest % NCOL, s = rest / NCOL;
  int b = n / NPOW;
  float v;
  if (k < E_) {
    int loc = locs_ix[n*MAXL + s];
    v = x[((size_t)(b*NLOC + loc))*E_ + k];
  } else {
    v = msg_emb[b*E_ + (k - E_)];
  }
  seq[idx] = v;
}

// ---------------- message embedding: msg_emb[b][n] = relu(msg_log[b,:] . msg_W[n,:] + msg_b[n]) ----
__global__ __launch_bounds__(256) void msgemb_kernel(
    const float* __restrict__ msg_log,  // [32][2000]
    const float* __restrict__ msg_W,    // [224][2000]
    const float* __restrict__ msg_b,
    float* __restrict__ msg_emb) {      // [32][224]
  int n = blockIdx.x;
  __shared__ float Wrow[MSGK];
  for (int i = threadIdx.x; i < MSGK; i += 256)
    Wrow[i] = msg_W[(size_t)n*MSGK + i];
  __syncthreads();
  int wave = threadIdx.x >> 6, lane = threadIdx.x & 63;
  int b0 = wave * 8;                    // 4 waves x 8 batch rows
  float acc[8] = {};
  for (int k = lane; k < MSGK; k += 64) {
    float w = Wrow[k];
#pragma unroll
    for (int r = 0; r < 8; ++r)
      acc[r] += w * msg_log[(size_t)(b0 + r)*MSGK + k];
  }
#pragma unroll
  for (int r = 0; r < 8; ++r) {
    float s = acc[r];
    for (int off = 32; off; off >>= 1) s += __shfl_xor(s, off);
    if (lane == 0) msg_emb[(size_t)(b0 + r)*E_ + n] = fmaxf(s + msg_b[n], 0.f);
  }
}

// ---------------- zero-fill dead (masked) dist rows ----------------
__global__ __launch_bounds__(256) void fill_dead_kernel(const int* __restrict__ locs_len,
                                                        float* __restrict__ out) {
  int gm = blockIdx.x;              // 0..NROW-1
  int n = gm / MAXL, s = gm % MAXL;
  if (s < locs_len[n]) return;
  float2* row = (float2*)(out + (size_t)gm*NACT);
  for (int i = threadIdx.x; i < NACT/2; i += 256)
    row[i] = make_float2(0.f, 0.f);
}

// ---------------- live-rows policy GEMM: 128x128x8 tile, 8x8 microtile (2x2 of 4x4) ----------------
#define PBM 128
#define PBN 128
#define PBK 8
__global__ __launch_bounds__(256) void pol_live_kernel(
    const float* __restrict__ hs, const float* __restrict__ pol_W,
    const float* __restrict__ pol_b, float* __restrict__ out) {
  int nlive = g_nlive;
  int row0 = blockIdx.y * PBM;
  if (row0 >= nlive) return;
  int col0 = blockIdx.x * PBN;
  __shared__ float As[PBK][PBM+4];
  __shared__ float Ws[PBK][PBN+4];
  __shared__ int rmap[PBM];
  int tid = threadIdx.x;
  for (int i = tid; i < PBM; i += 256) {
    int r = row0 + i;
    rmap[i] = (r < nlive) ? g_rowmap[r] : -1;
  }
  __syncthreads();
  int tx = tid & 15, ty = tid >> 4;
  int ms = tid >> 1, kq = tid & 1;      // staging: 128 rows x 2 half-k
  int gn_s = col0 + ms;
  float acc[2][2][4][4] = {};
  for (int k0 = 0; k0 < LSTM_H; k0 += PBK) {
    // ---- stage A (gathered live rows) and W ----
    {
      int gm = rmap[ms];
      float4 av = make_float4(0.f, 0.f, 0.f, 0.f);
      if (gm >= 0) av = *(const float4*)(hs + (size_t)gm*LSTM_H + k0 + kq*4);
      As[kq*4+0][ms] = av.x; As[kq*4+1][ms] = av.y;
      As[kq*4+2][ms] = av.z; As[kq*4+3][ms] = av.w;
      float4 wv = make_float4(0.f, 0.f, 0.f, 0.f);
      if (gn_s < NACT) wv = *(const float4*)(pol_W + (size_t)gn_s*LSTM_H + k0 + kq*4);
      Ws[kq*4+0][ms] = wv.x; Ws[kq*4+1][ms] = wv.y;
      Ws[kq*4+2][ms] = wv.z; Ws[kq*4+3][ms] = wv.w;
    }
    __syncthreads();
#pragma unroll
    for (int kk = 0; kk < PBK; ++kk) {
      float4 a0 = *(const float4*)&As[kk][ty*4];
      float4 a1 = *(const float4*)&As[kk][64 + ty*4];
      float4 w0 = *(const float4*)&Ws[kk][tx*4];
      float4 w1 = *(const float4*)&Ws[kk][64 + tx*4];
      float a_[2][4] = {{a0.x,a0.y,a0.z,a0.w},{a1.x,a1.y,a1.z,a1.w}};
      float w_[2][4] = {{w0.x,w0.y,w0.z,w0.w},{w1.x,w1.y,w1.z,w1.w}};
#pragma unroll
      for (int p = 0; p < 2; ++p)
#pragma unroll
        for (int q = 0; q < 2; ++q)
#pragma unroll
          for (int i = 0; i < 4; ++i)
#pragma unroll
            for (int j = 0; j < 4; ++j)
              acc[p][q][i][j] += a_[p][i] * w_[q][j];
    }
    __syncthreads();
  }
#pragma unroll
  for (int p = 0; p < 2; ++p)
#pragma unroll
    for (int i = 0; i < 4; ++i) {
      int rc = p*64 + ty*4 + i;
      if (row0 + rc >= nlive) continue;
      int gm = rmap[rc];
      float* orow = out + (size_t)gm*NACT;
#pragma unroll
      for (int q = 0; q < 2; ++q)
#pragma unroll
        for (int j = 0; j < 4; ++j) {
          int gn = col0 + q*64 + tx*4 + j;
          if (gn < NACT) orow[gn] = acc[p][q][i][j] + pol_b[gn];
        }
    }
}

// ---------------- two-layer LSTM v5: f32 weights, ONE column per block (224 blocks) ----------
__global__ __launch_bounds__(832) void lstm5_kernel(
    const float* __restrict__ gates0,   // [17*224][800] = seq@Wih0^T + bih0
    const float4* __restrict__ WTP0,    // [50][800]
    const float4* __restrict__ WTP1,    // [100][800]
    const float* __restrict__ bhh0,
    const float* __restrict__ bih1, const float* __restrict__ bhh1,
    float* __restrict__ hs) {           // [224][17][200]
  int n = blockIdx.x;
  int tid = threadIdx.x;
  __shared__ float hx[400];             // [0:200]=h_l0, [200:400]=h_l1
  __shared__ float gar[800];
  for (int i = tid; i < 400; i += 832) hx[i] = 0.f;
  float bh0 = 0.f, b1s = 0.f;
  if (tid < 800) { bh0 = bhh0[tid]; b1s = bih1[tid] + bhh1[tid]; }
  float c0 = 0.f, c1 = 0.f;             // cell state, threads 0..199
  __syncthreads();
  for (int s = 0; s < MAXL; ++s) {
    // ---- layer0 gates: a = gates0_row + bhh0 + h0 @ Whh0^T ----
    if (tid < 800) {
      float a = gates0[((size_t)s*NCOL + n)*800 + tid] + bh0;
      const float4* w = WTP0 + tid;
#pragma unroll 5
      for (int k4 = 0; k4 < 50; ++k4) {
        float4 wv = w[(size_t)k4*800];
        float4 ha = *(const float4*)&hx[k4*4];
        a += ha.x*wv.x + ha.y*wv.y + ha.z*wv.z + ha.w*wv.w;
      }
      gar[tid] = a;
    }
    __syncthreads();
    // ---- layer0 update ----
    if (tid < 200) {
      float ig = sigm(gar[tid]);
      float fg = sigm(gar[200 + tid]);
      float gg = tanhf(gar[400 + tid]);
      float og = sigm(gar[600 + tid]);
      c0 = fg*c0 + ig*gg;
      hx[tid] = og * tanhf(c0);
    }
    __syncthreads();
    // ---- layer1 gates: a = bih1+bhh1 + h0 @ Wih1^T + h1 @ Whh1^T ----
    if (tid < 800) {
      float a = b1s;
      const float4* w = WTP1 + tid;
#pragma unroll 5
      for (int k4 = 0; k4 < 100; ++k4) {
        float4 wv = w[(size_t)k4*800];
        float4 ha = *(const float4*)&hx[k4*4];
        a += ha.x*wv.x + ha.y*wv.y + ha.z*wv.z + ha.w*wv.w;
      }
      gar[tid] = a;
    }
    __syncthreads();
    // ---- layer1 update + emit hs ----
    if (tid < 200) {
      float ig = sigm(gar[tid]);
      float fg = sigm(gar[200 + tid]);
      float gg = tanhf(gar[400 + tid]);
      float og = sigm(gar[600 + tid]);
      c1 = fg*c1 + ig*gg;
      float hh = og * tanhf(c1);
      hx[200 + tid] = hh;
      hs[((size_t)n*MAXL + s)*LSTM_H + tid] = hh;
    }
    __syncthreads();
  }
}

// ---------------- lin1 split-K partials: P[sk][32][224] ----------------
__global__ __launch_bounds__(256) void lin1_partial_kernel(
    const float* __restrict__ x, const float* __restrict__ msg_emb,
    const float* __restrict__ W, float* __restrict__ P) {
  const int K = NLOC*E_ + E_;   // 18368
  const int chunk = 1148;       // 16 * 1148 = 18368
  int sk = blockIdx.z;
  int kb = sk*chunk, ke = kb + chunk;
  int col0 = blockIdx.x*32;
  __shared__ float As[16][36];
  __shared__ float Ws[16][36];
  int tid = threadIdx.x;
  int tx = tid & 15, ty = tid >> 4;
  float a00=0.f, a01=0.f, a10=0.f, a11=0.f;
  for (int k0 = kb; k0 < ke; k0 += 16) {
    for (int i = tid; i < 32*16; i += 256) {
      int m = i >> 4, kk = i & 15;
      int gk = k0 + kk;
      float v = 0.f;
      if (gk < ke) v = (gk < NLOC*E_) ? x[(size_t)m*(NLOC*E_) + gk] : msg_emb[m*E_ + gk - NLOC*E_];
      As[kk][m] = v;
      int n = col0 + m;
      Ws[kk][m] = (gk < ke) ? W[(size_t)n*K + gk] : 0.f;
    }
    __syncthreads();
#pragma unroll
    for (int kk = 0; kk < 16; ++kk) {
      float a0 = As[kk][ty*2], a1 = As[kk][ty*2+1];
      float w0 = Ws[kk][tx*2], w1 = Ws[kk][tx*2+1];
      a00 += a0*w0; a01 += a0*w1; a10 += a1*w0; a11 += a1*w1;
    }
    __syncthreads();
  }
  float* Pd = P + (size_t)sk*32*224;
  Pd[(ty*2  )*224 + col0 + tx*2  ] = a00;
  Pd[(ty*2  )*224 + col0 + tx*2+1] = a01;
  Pd[(ty*2+1)*224 + col0 + tx*2  ] = a10;
  Pd[(ty*2+1)*224 + col0 + tx*2+1] = a11;
}

// ---------------- value finalize: relu(sum P + b) @ lin2^T + b2 -> out f32 ----------------
__global__ __launch_bounds__(256) void value_finalize_kernel(
    const float* __restrict__ P, const float* __restrict__ lin1_b,
    const float* __restrict__ lin2_W, const float* __restrict__ lin2_b,
    float* __restrict__ out) {
  __shared__ float v1[32*224];
  for (int idx = threadIdx.x; idx < 32*224; idx += 256) {
    float s = 0.f;
    for (int sk = 0; sk < 16; ++sk) s += P[(size_t)sk*32*224 + idx];
    s += lin1_b[idx % 224];
    v1[idx] = fmaxf(s, 0.f);
  }
  __syncthreads();
  if (threadIdx.x < 32*NPOW) {
    int m = threadIdx.x / NPOW, q = threadIdx.x % NPOW;
    float s = lin2_b[q];
    for (int n = 0; n < E_; ++n) s += v1[m*224 + n] * lin2_W[q*E_ + n];
    out[m*NPOW + q] = s;
  }
}

extern "C" void kernel_launch(void* const* d_in, const int* in_sizes, int n_in,
                              void* d_out, int out_size, void* d_ws, size_t ws_size,
                              hipStream_t stream) {
  (void)in_sizes; (void)n_in; (void)out_size; (void)ws_size;
  const float* x_bo    = (const float*)d_in[0];
  const float* x_po    = (const float*)d_in[1];
  const float* msg_log = (const float*)d_in[2];
  const float* enc_W   = (const float*)d_in[3];
  const float* enc_b   = (const float*)d_in[4];
  const float* pos_bias= (const float*)d_in[5];
  const float* Wqkv    = (const float*)d_in[6];
  const float* bqkv    = (const float*)d_in[7];
  const float* Wo      = (const float*)d_in[8];
  const float* bo      = (const float*)d_in[9];
  const float* ln1_g   = (const float*)d_in[10];
  const float* ln1_b   = (const float*)d_in[11];
  const float* W1      = (const float*)d_in[12];
  const float* b1      = (const float*)d_in[13];
  const float* W2      = (const float*)d_in[14];
  const float* b2      = (const float*)d_in[15];
  const float* ln2_g   = (const float*)d_in[16];
  const float* ln2_b   = (const float*)d_in[17];
  const float* msg_W   = (const float*)d_in[18];
  const float* msg_b   = (const float*)d_in[19];
  const float* Wih0    = (const float*)d_in[20];
  const float* Whh0    = (const float*)d_in[21];
  const float* bih0    = (const float*)d_in[22];
  const float* bhh0    = (const float*)d_in[23];
  const float* Wih1    = (const float*)d_in[24];
  const float* Whh1    = (const float*)d_in[25];
  const float* bih1    = (const float*)d_in[26];
  const float* bhh1    = (const float*)d_in[27];
  const float* pol_W   = (const float*)d_in[28];
  const float* pol_b   = (const float*)d_in[29];
  const float* lin1_W  = (const float*)d_in[30];
  const float* lin1_b  = (const float*)d_in[31];
  const float* lin2_W  = (const float*)d_in[32];
  const float* lin2_b  = (const float*)d_in[33];
  const int*   locs_ix = (const int*)d_in[34];
  const int*   locs_len= (const int*)d_in[35];

  // ---- persistent scratch in ws (~5.9 MB) ----
  float* ws = (float*)d_ws;
  float* x        = ws;                    // 580608
  float* msg_emb  = ws + 580608;           // 7168
  float* P        = ws + 587776;           // 114688 -> ends 702464
  float* hs       = ws + 702464;           // 761600 -> ends 1464064

  // ---- large transient scratch inside d_out's f32 dist region (49.6M f32 slots,
  //      fully rewritten by fill_dead + pol_live at the end) ----
  float* os = (float*)d_out;
  float* qkv      = os;                    // 1741824
  float* attn_o   = os + 1741824;          // 580608
  float* tmp      = os + 2322432;          // 580608
  float* ff1      = os + 2903040;          // 580608 -> ends 3483648
  float* seq      = os;                    // 1705984 (reuses qkv area after transformer)
  float* gates0   = os + 3483648;          // 3046400 -> ends 6530048
  float4* WTP0    = (float4*)(os + 6530048);  // 160000 f32 -> ends 6690048
  float4* WTP1    = (float4*)(os + 6690048);  // 320000 f32 -> ends 7010048 (< 49618240)
  float* out      = (float*)d_out;

  // ---- fused prep: encoder + f32 weight pack + live-row scan (independent blocks) ----
  prep_kernel<<<TOK + TRANSW_BLOCKS + 1, 256, 0, stream>>>(
      x_bo, x_po, enc_W, enc_b, pos_bias, x, Whh0, Wih1, Whh1, WTP0, WTP1, locs_len);

  // ---- transformer layers ----
  for (int l = 0; l < NLAYERS; ++l) {
    gemm_kernel<0><<<dim3(11, 41), 256, 0, stream>>>(
        x, Wqkv + (size_t)l*672*224, bqkv + l*672, qkv, TOK, 672, 224);
    attn_kernel<<<B_*NH_*4, 256, 0, stream>>>(qkv, attn_o);
    gemm_kernel<0><<<dim3(4, 41), 256, 0, stream>>>(
        attn_o, Wo + (size_t)l*224*224, bo + l*224, tmp, TOK, 224, 224);
    addln_kernel<<<TOK, 256, 0, stream>>>(x, tmp, ln1_g + l*224, ln1_b + l*224);
    gemm_kernel<1><<<dim3(4, 41), 256, 0, stream>>>(
        x, W1 + (size_t)l*224*224, b1 + l*224, ff1, TOK, 224, 224);
    gemm_kernel<0><<<dim3(4, 41), 256, 0, stream>>>(
        ff1, W2 + (size_t)l*224*224, b2 + l*224, tmp, TOK, 224, 224);
    addln_kernel<<<TOK, 256, 0, stream>>>(x, tmp, ln2_g + l*224, ln2_b + l*224);
  }

  // ---- message embedding: relu(msg_log @ msg_W^T + msg_b), 224 blocks ----
  msgemb_kernel<<<E_, 256, 0, stream>>>(msg_log, msg_W, msg_b, msg_emb);

  // ---- LSTM input sequence + hoisted input-gate GEMM ----
  gather_kernel<<<(MAXL*NCOL*448 + 255)/256, 256, 0, stream>>>(x, msg_emb, locs_ix, seq);
  gemm_kernel<0><<<dim3(13, 60), 256, 0, stream>>>(seq, Wih0, bih0, gates0, NROW, 800, 448);
  lstm5_kernel<<<NCOL, 832, 0, stream>>>(gates0, WTP0, WTP1, bhh0, bih1, bhh1, hs);

  // ---- policy head: zero dead rows (BW-bound) + GEMM only live rows ----
  fill_dead_kernel<<<NROW, 256, 0, stream>>>(locs_len, out);
  pol_live_kernel<<<dim3((NACT + PBN - 1)/PBN, (NROW + PBM - 1)/PBM), 256, 0, stream>>>(
      hs, pol_W, pol_b, out);

  // ---- value head ----
  lin1_partial_kernel<<<dim3(7, 1, 16), 256, 0, stream>>>(x, msg_emb, lin1_W, P);
  value_finalize_kernel<<<1, 256, 0, stream>>>(P, lin1_b, lin2_W, lin2_b, out + (size_t)DIST_SIZE);
}

// Round 12
// 2234.428 us; speedup vs baseline: 1.5202x; 1.2672x over previous
//
#include <hip/hip_runtime.h>
#include <hip/hip_bf16.h>
#include <math.h>

#define B_ 32
#define NLOC 81
#define SBO 35
#define SPO 40
#define E_ 224
#define NH_ 8
#define DH 28
#define NLAYERS 10
#define LSTM_H 200
#define NACT 13030
#define NPOW 7
#define MAXL 17
#define TOK (B_*NLOC)          // 2592
#define NCOL (B_*NPOW)         // 224
#define NROW (NCOL*MAXL)       // 3808
#define DIST_SIZE (B_*NPOW*MAXL*NACT)  // 49618240 f32 elements
#define MSGK 2000              // MSGLOG*MSGEMB
#define TRANSW_BLOCKS ((100*800 + 255)/256)   // 313
#define FR 16                  // rows per mlp_fused block (162 blocks)

__device__ __forceinline__ float sigm(float x) { return 1.f / (1.f + __expf(-x)); }

// ---- device-global compaction state (graph-safe, no hipMalloc) ----
__device__ int g_rowmap[NROW];
__device__ int g_nlive;

// ---------------- prep: encoder + recurrent-weight pack (f32) + live-row scan ----------------
__global__ __launch_bounds__(256) void prep_kernel(
    const float* __restrict__ x_bo, const float* __restrict__ x_po,
    const float* __restrict__ enc_W, const float* __restrict__ enc_b,
    const float* __restrict__ pos_bias, float* __restrict__ x,
    const float* __restrict__ Whh0, const float* __restrict__ Wih1,
    const float* __restrict__ Whh1, float4* __restrict__ WTP0,
    float4* __restrict__ WTP1, const int* __restrict__ locs_len) {
  int bid = blockIdx.x;
  if (bid < TOK) {
    int t = bid;
    int l = t % NLOC;
    __shared__ float in[SBO + SPO];
    if (threadIdx.x < SBO) in[threadIdx.x] = x_bo[(size_t)t*SBO + threadIdx.x];
    else if (threadIdx.x < SBO + SPO) in[threadIdx.x] = x_po[(size_t)t*SPO + threadIdx.x - SBO];
    __syncthreads();
    int e = threadIdx.x;
    if (e < E_) {
      float s = enc_b[e] + pos_bias[l*E_ + e];
      const float* w = enc_W + e*(SBO+SPO);
      for (int k = 0; k < SBO+SPO; ++k) s += in[k] * w[k];
      x[(size_t)t*E_ + e] = s;
    }
  } else if (bid < TOK + TRANSW_BLOCKS) {
    int idx = (bid - TOK)*256 + threadIdx.x;   // over 100*800
    if (idx >= 100*800) return;
    int k4 = idx / 800, g = idx % 800;
    const float* src = (k4 < 50) ? (Wih1 + (size_t)g*LSTM_H + 4*k4)
                                 : (Whh1 + (size_t)g*LSTM_H + 4*k4 - 200);
    WTP1[idx] = make_float4(src[0], src[1], src[2], src[3]);
    if (k4 < 50) {
      const float* s0 = Whh0 + (size_t)g*LSTM_H + 4*k4;
      WTP0[idx] = make_float4(s0[0], s0[1], s0[2], s0[3]);
    }
  } else {
    __shared__ int off[NCOL + 1];
    if (threadIdx.x == 0) {
      int acc = 0;
      for (int n = 0; n < NCOL; ++n) { off[n] = acc; acc += locs_len[n]; }
      off[NCOL] = acc;
      g_nlive = acc;
    }
    __syncthreads();
    for (int n = threadIdx.x; n < NCOL; n += 256) {
      int base = off[n], len = locs_len[n];
      for (int s = 0; s < len; ++s) g_rowmap[base + s] = n*MAXL + s;
    }
  }
}

// ---------------- generic GEMM: C[M,N] = A[M,K](f32) @ W[N,K]^T(f32) + bias ----------------
#define GBM 64
#define GBN 64
#define GBK 16
template<int RELU>
__global__ __launch_bounds__(256) void gemm_kernel(
    const float* __restrict__ A, const float* __restrict__ W,
    const float* __restrict__ bias, float* __restrict__ C,
    int M, int N, int K) {
  __shared__ float As[GBK][GBM+4];
  __shared__ float Ws[GBK][GBN+4];
  int tid = threadIdx.x;
  int tx = tid & 15, ty = tid >> 4;
  int row0 = blockIdx.y * GBM, col0 = blockIdx.x * GBN;
  float acc[4][4] = {};
  for (int k0 = 0; k0 < K; k0 += GBK) {
    for (int i = tid; i < GBM*GBK; i += 256) {
      int m = i >> 4, kk = i & 15;
      int gm = row0 + m, gk = k0 + kk;
      As[kk][m] = (gm < M && gk < K) ? A[(size_t)gm*K + gk] : 0.f;
    }
    for (int i = tid; i < GBN*GBK; i += 256) {
      int n = i >> 4, kk = i & 15;
      int gn = col0 + n, gk = k0 + kk;
      Ws[kk][n] = (gn < N && gk < K) ? W[(size_t)gn*K + gk] : 0.f;
    }
    __syncthreads();
#pragma unroll
    for (int kk = 0; kk < GBK; ++kk) {
      float4 av = *(const float4*)&As[kk][ty*4];
      float4 wv = *(const float4*)&Ws[kk][tx*4];
      float a_[4] = {av.x, av.y, av.z, av.w};
      float w_[4] = {wv.x, wv.y, wv.z, wv.w};
#pragma unroll
      for (int i = 0; i < 4; ++i)
#pragma unroll
        for (int j = 0; j < 4; ++j)
          acc[i][j] += a_[i] * w_[j];
    }
    __syncthreads();
  }
#pragma unroll
  for (int i = 0; i < 4; ++i) {
    int gm = row0 + ty*4 + i;
    if (gm >= M) continue;
#pragma unroll
    for (int j = 0; j < 4; ++j) {
      int gn = col0 + tx*4 + j;
      if (gn >= N) continue;
      float v = acc[i][j] + (bias ? bias[gn] : 0.f);
      if (RELU) v = fmaxf(v, 0.f);
      C[(size_t)gm*N + gn] = v;
    }
  }
}

// ---------------- attention v2: 4 blocks per (b,h), split-half PV ----------------
__global__ __launch_bounds__(256) void attn_kernel(const float* __restrict__ qkv,
                                                   float* __restrict__ attn_o) {
  int bh = blockIdx.x >> 2;
  int chunk = blockIdx.x & 3;
  int b = bh / NH_, h = bh % NH_;
  __shared__ float Qs[NLOC][DH];
  __shared__ float Ks[NLOC][DH+1];
  __shared__ float Vs[NLOC][DH+1];
  __shared__ float Ps[4][NLOC];
  for (int i = threadIdx.x; i < NLOC*DH; i += 256) {
    int l = i / DH, d = i % DH;
    const float* base = qkv + ((size_t)(b*NLOC + l))*(3*E_);
    Qs[l][d] = base[h*DH + d];
    Ks[l][d] = base[E_ + h*DH + d];
    Vs[l][d] = base[2*E_ + h*DH + d];
  }
  __syncthreads();
  int wave = threadIdx.x >> 6, lane = threadIdx.x & 63;
  int half = lane >> 5, dd = lane & 31;
  const float scale = 0.1889822365046136f;  // 1/sqrt(28)
  for (int l = wave + chunk*4; l < NLOC; l += 16) {
    int j0 = lane, j1 = lane + 64;
    bool has1 = (j1 < NLOC);
    int j1c = has1 ? j1 : 0;
    float s0 = 0.f, s1 = 0.f;
    for (int d = 0; d < DH; ++d) {
      float q = Qs[l][d];
      s0 += q * Ks[j0][d];
      s1 += q * Ks[j1c][d];
    }
    s0 *= scale; s1 *= scale;
    float m = fmaxf(s0, has1 ? s1 : -1e30f);
    for (int off = 32; off; off >>= 1) m = fmaxf(m, __shfl_xor(m, off));
    float p0 = __expf(s0 - m);
    float p1 = has1 ? __expf(s1 - m) : 0.f;
    float sum = p0 + p1;
    for (int off = 32; off; off >>= 1) sum += __shfl_xor(sum, off);
    float inv = 1.f / sum;
    Ps[wave][j0] = p0 * inv;
    if (has1) Ps[wave][j1] = p1 * inv;
    float o = 0.f;
    int jend = half ? NLOC : 41;
    bool dok = (dd < DH);
    for (int j = half*41; j < jend; ++j) {
      float p = Ps[wave][j];
      float vv = dok ? Vs[j][dd] : 0.f;
      o += p * vv;
    }
    o += __shfl_xor(o, 32);
    if (lane < DH)
      attn_o[((size_t)(b*NLOC + l))*E_ + h*DH + lane] = o;
  }
}

// ---------------- chunk GEMM helper for mlp_fused: acc = aT(k-major) @ Wmat^T chunk-wise ----
// #pragma unroll 1 on the k0 loop bounds code size (hipcc would otherwise fully unroll
// 14x16x16 FMA x 3 call sites -> compile blowup; suspected cause of r11 harness timeout).
__device__ __forceinline__ void chunk_gemm224(
    const float* __restrict__ Wmat, const float* aT, float* Wd,
    int t, int n0, int rq, float acc[4][4]) {
#pragma unroll
  for (int i = 0; i < 4; ++i)
#pragma unroll
    for (int j = 0; j < 4; ++j) acc[i][j] = 0.f;
#pragma unroll 1
  for (int k0 = 0; k0 < E_; k0 += 16) {
    {
      const float* wrow = Wmat + (size_t)t*E_ + k0;
      float4 q0 = *(const float4*)(wrow);
      float4 q1 = *(const float4*)(wrow + 4);
      float4 q2 = *(const float4*)(wrow + 8);
      float4 q3 = *(const float4*)(wrow + 12);
      float wv[16] = {q0.x,q0.y,q0.z,q0.w, q1.x,q1.y,q1.z,q1.w,
                      q2.x,q2.y,q2.z,q2.w, q3.x,q3.y,q3.z,q3.w};
#pragma unroll
      for (int kk = 0; kk < 16; ++kk) Wd[kk*224 + t] = wv[kk];
    }
    __syncthreads();
#pragma unroll
    for (int kk = 0; kk < 16; ++kk) {
      float4 wv4 = *(const float4*)&Wd[kk*224 + n0];
      float4 av4 = *(const float4*)&aT[(k0 + kk)*20 + rq*4];
      float a_[4] = {av4.x, av4.y, av4.z, av4.w};
      float w_[4] = {wv4.x, wv4.y, wv4.z, wv4.w};
#pragma unroll
      for (int i = 0; i < 4; ++i)
#pragma unroll
        for (int j = 0; j < 4; ++j) acc[i][j] += a_[i] * w_[j];
    }
    __syncthreads();
  }
}

// ---------------- fused MLP block: x = LN2( x' + relu(x'@W1^T+b1)@W2^T+b2 ),
//                  x' = LN1( x + attn_o@Wo^T+bo )   -- 16 full rows per block ----
__global__ __launch_bounds__(224) void mlp_fused_kernel(
    const float* __restrict__ attn_o, const float* __restrict__ Wo,
    const float* __restrict__ bo, const float* __restrict__ ln1_g,
    const float* __restrict__ ln1_b, const float* __restrict__ W1,
    const float* __restrict__ b1, const float* __restrict__ W2,
    const float* __restrict__ b2, const float* __restrict__ ln2_g,
    const float* __restrict__ ln2_b, float* __restrict__ x) {
  int r0 = blockIdx.x * FR;
  int t = threadIdx.x;
  int nq = t % 56, rq = t / 56;
  int n0 = nq * 4;
  __shared__ float aT[224*20];      // operand, k-major: aT[k*20 + r]
  __shared__ float Wd[16*224];      // weight chunk, k-major: Wd[kk*224 + n]
  __shared__ float xr[FR][224];     // residual rows (row-major)
  __shared__ float red1[FR][57];
  __shared__ float red2[FR][57];
  __shared__ float mrs[FR][2];
  for (int r = 0; r < FR; ++r) {
    xr[r][t] = x[(size_t)(r0 + r)*E_ + t];
    aT[t*20 + r] = attn_o[(size_t)(r0 + r)*E_ + t];
  }
  __syncthreads();
  float acc[4][4];

  // ===== phase A: Wo + residual + LN1 =====
  chunk_gemm224(Wo, aT, Wd, t, n0, rq, acc);
  {
    float gv[4], bv[4], bov[4];
#pragma unroll
    for (int j = 0; j < 4; ++j) { gv[j] = ln1_g[n0+j]; bv[j] = ln1_b[n0+j]; bov[j] = bo[n0+j]; }
#pragma unroll
    for (int i = 0; i < 4; ++i) {
      int r = rq*4 + i;
      float s = 0.f, s2 = 0.f;
#pragma unroll
      for (int j = 0; j < 4; ++j) {
        float v = xr[r][n0+j] + acc[i][j] + bov[j];
        acc[i][j] = v; s += v; s2 += v*v;
      }
      red1[r][nq] = s; red2[r][nq] = s2;
    }
    __syncthreads();
    if (t < FR) {
      float s = 0.f, s2 = 0.f;
      for (int c = 0; c < 56; ++c) { s += red1[t][c]; s2 += red2[t][c]; }
      float m = s / E_;
      mrs[t][0] = m;
      mrs[t][1] = rsqrtf(s2 / E_ - m*m + 1e-5f);
    }
    __syncthreads();
#pragma unroll
    for (int i = 0; i < 4; ++i) {
      int r = rq*4 + i;
      float m = mrs[r][0], rs = mrs[r][1];
#pragma unroll
      for (int j = 0; j < 4; ++j) {
        float v = (acc[i][j] - m) * rs * gv[j] + bv[j];
        xr[r][n0+j] = v;            // residual for LN2
        aT[(n0+j)*20 + r] = v;      // operand for W1
      }
    }
    __syncthreads();
  }
  // ===== phase B: W1 + relu =====
  chunk_gemm224(W1, aT, Wd, t, n0, rq, acc);
  {
    float b1v[4];
#pragma unroll
    for (int j = 0; j < 4; ++j) b1v[j] = b1[n0+j];
#pragma unroll
    for (int i = 0; i < 4; ++i)
#pragma unroll
      for (int j = 0; j < 4; ++j)
        acc[i][j] = fmaxf(acc[i][j] + b1v[j], 0.f);
    __syncthreads();                 // all reads of aT (x') done
#pragma unroll
    for (int i = 0; i < 4; ++i) {
      int r = rq*4 + i;
#pragma unroll
      for (int j = 0; j < 4; ++j)
        aT[(n0+j)*20 + r] = acc[i][j];   // ff^T: operand for W2
    }
    __syncthreads();
  }
  // ===== phase C: W2 + residual(x') + LN2 -> global x =====
  chunk_gemm224(W2, aT, Wd, t, n0, rq, acc);
  {
    float gv[4], bv[4], b2v[4];
#pragma unroll
    for (int j = 0; j < 4; ++j) { gv[j] = ln2_g[n0+j]; bv[j] = ln2_b[n0+j]; b2v[j] = b2[n0+j]; }
#pragma unroll
    for (int i = 0; i < 4; ++i) {
      int r = rq*4 + i;
      float s = 0.f, s2 = 0.f;
#pragma unroll
      for (int j = 0; j < 4; ++j) {
        float v = xr[r][n0+j] + acc[i][j] + b2v[j];
        acc[i][j] = v; s += v; s2 += v*v;
      }
      red1[r][nq] = s; red2[r][nq] = s2;
    }
    __syncthreads();
    if (t < FR) {
      float s = 0.f, s2 = 0.f;
      for (int c = 0; c < 56; ++c) { s += red1[t][c]; s2 += red2[t][c]; }
      float m = s / E_;
      mrs[t][0] = m;
      mrs[t][1] = rsqrtf(s2 / E_ - m*m + 1e-5f);
    }
    __syncthreads();
#pragma unroll
    for (int i = 0; i < 4; ++i) {
      int r = rq*4 + i;
      float m = mrs[r][0], rs = mrs[r][1];
      float4 o;
      o.x = (acc[i][0] - m) * rs * gv[0] + bv[0];
      o.y = (acc[i][1] - m) * rs * gv[1] + bv[1];
      o.z = (acc[i][2] - m) * rs * gv[2] + bv[2];
      o.w = (acc[i][3] - m) * rs * gv[3] + bv[3];
      *(float4*)&x[(size_t)(r0 + r)*E_ + n0] = o;
    }
  }
}

// ---------------- gather: seq[s][n][0:224]=x[b,locs_ix], [224:448]=msg_emb[b] ----------------
__global__ void gather_kernel(const float* __restrict__ x, const float* __restrict__ msg_emb,
                              const int* __restrict__ locs_ix, float* __restrict__ seq) {
  int idx = blockIdx.x*256 + threadIdx.x;
  if (idx >= MAXL*NCOL*(2*E_)) return;
  int k = idx % (2*E_);
  int rest = idx / (2*E_);
  int n = rest % NCOL, s = rest / NCOL;
  int b = n / NPOW;
  float v;
  if (k < E_) {
    int loc = locs_ix[n*MAXL + s];
    v = x[((size_t)(b*NLOC + loc))*E_ + k];
  } else {
    v = msg_emb[b*E_ + (k - E_)];
  }
  seq[idx] = v;
}

// ---------------- message embedding ----------------
__global__ __launch_bounds__(256) void msgemb_kernel(
    const float* __restrict__ msg_log, const float* __restrict__ msg_W,
    const float* __restrict__ msg_b, float* __restrict__ msg_emb) {
  int n = blockIdx.x;
  __shared__ float Wrow[MSGK];
  for (int i = threadIdx.x; i < MSGK; i += 256)
    Wrow[i] = msg_W[(size_t)n*MSGK + i];
  __syncthreads();
  int wave = threadIdx.x >> 6, lane = threadIdx.x & 63;
  int b0 = wave * 8;
  float acc[8] = {};
  for (int k = lane; k < MSGK; k += 64) {
    float w = Wrow[k];
#pragma unroll
    for (int r = 0; r < 8; ++r)
      acc[r] += w * msg_log[(size_t)(b0 + r)*MSGK + k];
  }
#pragma unroll
  for (int r = 0; r < 8; ++r) {
    float s = acc[r];
    for (int off = 32; off; off >>= 1) s += __shfl_xor(s, off);
    if (lane == 0) msg_emb[(size_t)(b0 + r)*E_ + n] = fmaxf(s + msg_b[n], 0.f);
  }
}

// ---------------- zero-fill dead (masked) dist rows ----------------
__global__ __launch_bounds__(256) void fill_dead_kernel(const int* __restrict__ locs_len,
                                                        float* __restrict__ out) {
  int gm = blockIdx.x;
  int n = gm / MAXL, s = gm % MAXL;
  if (s < locs_len[n]) return;
  float2* row = (float2*)(out + (size_t)gm*NACT);
  for (int i = threadIdx.x; i < NACT/2; i += 256)
    row[i] = make_float2(0.f, 0.f);
}

// ---------------- live-rows policy GEMM: 128x128x8 tile, 8x8 microtile ----------------
#define PBM 128
#define PBN 128
#define PBK 8
__global__ __launch_bounds__(256) void pol_live_kernel(
    const float* __restrict__ hs, const float* __restrict__ pol_W,
    const float* __restrict__ pol_b, float* __restrict__ out) {
  int nlive = g_nlive;
  int row0 = blockIdx.y * PBM;
  if (row0 >= nlive) return;
  int col0 = blockIdx.x * PBN;
  __shared__ float As[PBK][PBM+4];
  __shared__ float Ws[PBK][PBN+4];
  __shared__ int rmap[PBM];
  int tid = threadIdx.x;
  for (int i = tid; i < PBM; i += 256) {
    int r = row0 + i;
    rmap[i] = (r < nlive) ? g_rowmap[r] : -1;
  }
  __syncthreads();
  int tx = tid & 15, ty = tid >> 4;
  int ms = tid >> 1, kq = tid & 1;
  int gn_s = col0 + ms;
  float acc[2][2][4][4] = {};
  for (int k0 = 0; k0 < LSTM_H; k0 += PBK) {
    {
      int gm = rmap[ms];
      float4 av = make_float4(0.f, 0.f, 0.f, 0.f);
      if (gm >= 0) av = *(const float4*)(hs + (size_t)gm*LSTM_H + k0 + kq*4);
      As[kq*4+0][ms] = av.x; As[kq*4+1][ms] = av.y;
      As[kq*4+2][ms] = av.z; As[kq*4+3][ms] = av.w;
      float4 wv = make_float4(0.f, 0.f, 0.f, 0.f);
      if (gn_s < NACT) wv = *(const float4*)(pol_W + (size_t)gn_s*LSTM_H + k0 + kq*4);
      Ws[kq*4+0][ms] = wv.x; Ws[kq*4+1][ms] = wv.y;
      Ws[kq*4+2][ms] = wv.z; Ws[kq*4+3][ms] = wv.w;
    }
    __syncthreads();
#pragma unroll
    for (int kk = 0; kk < PBK; ++kk) {
      float4 a0 = *(const float4*)&As[kk][ty*4];
      float4 a1 = *(const float4*)&As[kk][64 + ty*4];
      float4 w0 = *(const float4*)&Ws[kk][tx*4];
      float4 w1 = *(const float4*)&Ws[kk][64 + tx*4];
      float a_[2][4] = {{a0.x,a0.y,a0.z,a0.w},{a1.x,a1.y,a1.z,a1.w}};
      float w_[2][4] = {{w0.x,w0.y,w0.z,w0.w},{w1.x,w1.y,w1.z,w1.w}};
#pragma unroll
      for (int p = 0; p < 2; ++p)
#pragma unroll
        for (int q = 0; q < 2; ++q)
#pragma unroll
          for (int i = 0; i < 4; ++i)
#pragma unroll
            for (int j = 0; j < 4; ++j)
              acc[p][q][i][j] += a_[p][i] * w_[q][j];
    }
    __syncthreads();
  }
#pragma unroll
  for (int p = 0; p < 2; ++p)
#pragma unroll
    for (int i = 0; i < 4; ++i) {
      int rc = p*64 + ty*4 + i;
      if (row0 + rc >= nlive) continue;
      int gm = rmap[rc];
      float* orow = out + (size_t)gm*NACT;
#pragma unroll
      for (int q = 0; q < 2; ++q)
#pragma unroll
        for (int j = 0; j < 4; ++j) {
          int gn = col0 + q*64 + tx*4 + j;
          if (gn < NACT) orow[gn] = acc[p][q][i][j] + pol_b[gn];
        }
    }
}

// ---------------- two-layer LSTM v5: f32 weights, ONE column per block ----------------
__global__ __launch_bounds__(832) void lstm5_kernel(
    const float* __restrict__ gates0,
    const float4* __restrict__ WTP0, const float4* __restrict__ WTP1,
    const float* __restrict__ bhh0,
    const float* __restrict__ bih1, const float* __restrict__ bhh1,
    float* __restrict__ hs) {
  int n = blockIdx.x;
  int tid = threadIdx.x;
  __shared__ float hx[400];
  __shared__ float gar[800];
  for (int i = tid; i < 400; i += 832) hx[i] = 0.f;
  float bh0 = 0.f, b1s = 0.f;
  if (tid < 800) { bh0 = bhh0[tid]; b1s = bih1[tid] + bhh1[tid]; }
  float c0 = 0.f, c1 = 0.f;
  __syncthreads();
  for (int s = 0; s < MAXL; ++s) {
    if (tid < 800) {
      float a = gates0[((size_t)s*NCOL + n)*800 + tid] + bh0;
      const float4* w = WTP0 + tid;
#pragma unroll 5
      for (int k4 = 0; k4 < 50; ++k4) {
        float4 wv = w[(size_t)k4*800];
        float4 ha = *(const float4*)&hx[k4*4];
        a += ha.x*wv.x + ha.y*wv.y + ha.z*wv.z + ha.w*wv.w;
      }
      gar[tid] = a;
    }
    __syncthreads();
    if (tid < 200) {
      float ig = sigm(gar[tid]);
      float fg = sigm(gar[200 + tid]);
      float gg = tanhf(gar[400 + tid]);
      float og = sigm(gar[600 + tid]);
      c0 = fg*c0 + ig*gg;
      hx[tid] = og * tanhf(c0);
    }
    __syncthreads();
    if (tid < 800) {
      float a = b1s;
      const float4* w = WTP1 + tid;
#pragma unroll 5
      for (int k4 = 0; k4 < 100; ++k4) {
        float4 wv = w[(size_t)k4*800];
        float4 ha = *(const float4*)&hx[k4*4];
        a += ha.x*wv.x + ha.y*wv.y + ha.z*wv.z + ha.w*wv.w;
      }
      gar[tid] = a;
    }
    __syncthreads();
    if (tid < 200) {
      float ig = sigm(gar[tid]);
      float fg = sigm(gar[200 + tid]);
      float gg = tanhf(gar[400 + tid]);
      float og = sigm(gar[600 + tid]);
      c1 = fg*c1 + ig*gg;
      float hh = og * tanhf(c1);
      hx[200 + tid] = hh;
      hs[((size_t)n*MAXL + s)*LSTM_H + tid] = hh;
    }
    __syncthreads();
  }
}

// ---------------- lin1 split-K partials: P[sk][32][224] ----------------
__global__ __launch_bounds__(256) void lin1_partial_kernel(
    const float* __restrict__ x, const float* __restrict__ msg_emb,
    const float* __restrict__ W, float* __restrict__ P) {
  const int K = NLOC*E_ + E_;   // 18368
  const int chunk = 1148;
  int sk = blockIdx.z;
  int kb = sk*chunk, ke = kb + chunk;
  int col0 = blockIdx.x*32;
  __shared__ float As[16][36];
  __shared__ float Ws[16][36];
  int tid = threadIdx.x;
  int tx = tid & 15, ty = tid >> 4;
  float a00=0.f, a01=0.f, a10=0.f, a11=0.f;
  for (int k0 = kb; k0 < ke; k0 += 16) {
    for (int i = tid; i < 32*16; i += 256) {
      int m = i >> 4, kk = i & 15;
      int gk = k0 + kk;
      float v = 0.f;
      if (gk < ke) v = (gk < NLOC*E_) ? x[(size_t)m*(NLOC*E_) + gk] : msg_emb[m*E_ + gk - NLOC*E_];
      As[kk][m] = v;
      int n = col0 + m;
      Ws[kk][m] = (gk < ke) ? W[(size_t)n*K + gk] : 0.f;
    }
    __syncthreads();
#pragma unroll
    for (int kk = 0; kk < 16; ++kk) {
      float a0 = As[kk][ty*2], a1 = As[kk][ty*2+1];
      float w0 = Ws[kk][tx*2], w1 = Ws[kk][tx*2+1];
      a00 += a0*w0; a01 += a0*w1; a10 += a1*w0; a11 += a1*w1;
    }
    __syncthreads();
  }
  float* Pd = P + (size_t)sk*32*224;
  Pd[(ty*2  )*224 + col0 + tx*2  ] = a00;
  Pd[(ty*2  )*224 + col0 + tx*2+1] = a01;
  Pd[(ty*2+1)*224 + col0 + tx*2  ] = a10;
  Pd[(ty*2+1)*224 + col0 + tx*2+1] = a11;
}

// ---------------- value finalize ----------------
__global__ __launch_bounds__(256) void value_finalize_kernel(
    const float* __restrict__ P, const float* __restrict__ lin1_b,
    const float* __restrict__ lin2_W, const float* __restrict__ lin2_b,
    float* __restrict__ out) {
  __shared__ float v1[32*224];
  for (int idx = threadIdx.x; idx < 32*224; idx += 256) {
    float s = 0.f;
    for (int sk = 0; sk < 16; ++sk) s += P[(size_t)sk*32*224 + idx];
    s += lin1_b[idx % 224];
    v1[idx] = fmaxf(s, 0.f);
  }
  __syncthreads();
  if (threadIdx.x < 32*NPOW) {
    int m = threadIdx.x / NPOW, q = threadIdx.x % NPOW;
    float s = lin2_b[q];
    for (int n = 0; n < E_; ++n) s += v1[m*224 + n] * lin2_W[q*E_ + n];
    out[m*NPOW + q] = s;
  }
}

extern "C" void kernel_launch(void* const* d_in, const int* in_sizes, int n_in,
                              void* d_out, int out_size, void* d_ws, size_t ws_size,
                              hipStream_t stream) {
  (void)in_sizes; (void)n_in; (void)out_size; (void)ws_size;
  const float* x_bo    = (const float*)d_in[0];
  const float* x_po    = (const float*)d_in[1];
  const float* msg_log = (const float*)d_in[2];
  const float* enc_W   = (const float*)d_in[3];
  const float* enc_b   = (const float*)d_in[4];
  const float* pos_bias= (const float*)d_in[5];
  const float* Wqkv    = (const float*)d_in[6];
  const float* bqkv    = (const float*)d_in[7];
  const float* Wo      = (const float*)d_in[8];
  const float* bo      = (const float*)d_in[9];
  const float* ln1_g   = (const float*)d_in[10];
  const float* ln1_b   = (const float*)d_in[11];
  const float* W1      = (const float*)d_in[12];
  const float* b1      = (const float*)d_in[13];
  const float* W2      = (const float*)d_in[14];
  const float* b2      = (const float*)d_in[15];
  const float* ln2_g   = (const float*)d_in[16];
  const float* ln2_b   = (const float*)d_in[17];
  const float* msg_W   = (const float*)d_in[18];
  const float* msg_b   = (const float*)d_in[19];
  const float* Wih0    = (const float*)d_in[20];
  const float* Whh0    = (const float*)d_in[21];
  const float* bih0    = (const float*)d_in[22];
  const float* bhh0    = (const float*)d_in[23];
  const float* Wih1    = (const float*)d_in[24];
  const float* Whh1    = (const float*)d_in[25];
  const float* bih1    = (const float*)d_in[26];
  const float* bhh1    = (const float*)d_in[27];
  const float* pol_W   = (const float*)d_in[28];
  const float* pol_b   = (const float*)d_in[29];
  const float* lin1_W  = (const float*)d_in[30];
  const float* lin1_b  = (const float*)d_in[31];
  const float* lin2_W  = (const float*)d_in[32];
  const float* lin2_b  = (const float*)d_in[33];
  const int*   locs_ix = (const int*)d_in[34];
  const int*   locs_len= (const int*)d_in[35];

  // ---- persistent scratch in ws (~5.9 MB) ----
  float* ws = (float*)d_ws;
  float* x        = ws;                    // 580608
  float* msg_emb  = ws + 580608;           // 7168
  float* P        = ws + 587776;           // 114688 -> ends 702464
  float* hs       = ws + 702464;           // 761600 -> ends 1464064

  // ---- large transient scratch inside d_out's f32 dist region ----
  float* os = (float*)d_out;
  float* qkv      = os;                    // 1741824
  float* attn_o   = os + 1741824;          // 580608
  float* seq      = os;                    // reuses qkv area after transformer
  float* gates0   = os + 3483648;          // 3046400 -> ends 6530048
  float4* WTP0    = (float4*)(os + 6530048);  // 160000 f32 -> ends 6690048
  float4* WTP1    = (float4*)(os + 6690048);  // 320000 f32 -> ends 7010048 (< 49618240)
  float* out      = (float*)d_out;

  // ---- fused prep: encoder + f32 weight pack + live-row scan ----
  prep_kernel<<<TOK + TRANSW_BLOCKS + 1, 256, 0, stream>>>(
      x_bo, x_po, enc_W, enc_b, pos_bias, x, Whh0, Wih1, Whh1, WTP0, WTP1, locs_len);

  // ---- transformer layers: 3 dispatches/layer ----
  for (int l = 0; l < NLAYERS; ++l) {
    gemm_kernel<0><<<dim3(11, 41), 256, 0, stream>>>(
        x, Wqkv + (size_t)l*672*224, bqkv + l*672, qkv, TOK, 672, 224);
    attn_kernel<<<B_*NH_*4, 256, 0, stream>>>(qkv, attn_o);
    mlp_fused_kernel<<<TOK/FR, 224, 0, stream>>>(
        attn_o, Wo + (size_t)l*224*224, bo + l*224,
        ln1_g + l*224, ln1_b + l*224,
        W1 + (size_t)l*224*224, b1 + l*224,
        W2 + (size_t)l*224*224, b2 + l*224,
        ln2_g + l*224, ln2_b + l*224, x);
  }

  // ---- message embedding ----
  msgemb_kernel<<<E_, 256, 0, stream>>>(msg_log, msg_W, msg_b, msg_emb);

  // ---- LSTM input sequence + hoisted input-gate GEMM ----
  gather_kernel<<<(MAXL*NCOL*448 + 255)/256, 256, 0, stream>>>(x, msg_emb, locs_ix, seq);
  gemm_kernel<0><<<dim3(13, 60), 256, 0, stream>>>(seq, Wih0, bih0, gates0, NROW, 800, 448);
  lstm5_kernel<<<NCOL, 832, 0, stream>>>(gates0, WTP0, WTP1, bhh0, bih1, bhh1, hs);

  // ---- policy head ----
  fill_dead_kernel<<<NROW, 256, 0, stream>>>(locs_len, out);
  pol_live_kernel<<<dim3((NACT + PBN - 1)/PBN, (NROW + PBM - 1)/PBM), 256, 0, stream>>>(
      hs, pol_W, pol_b, out);

  // ---- value head ----
  lin1_partial_kernel<<<dim3(7, 1, 16), 256, 0, stream>>>(x, msg_emb, lin1_W, P);
  value_finalize_kernel<<<1, 256, 0, stream>>>(P, lin1_b, lin2_W, lin2_b, out + (size_t)DIST_SIZE);
}